// Round 5
// baseline (9061.621 us; speedup 1.0000x reference)
//
#include <hip/hip_runtime.h>
#include <stdint.h>
#include <stddef.h>

#define B_ 64
#define T_ 512
#define DIN 256
#define H_ 512
#define G4 2048      // 4*H
#define NWGF 128     // fused: 64 layer-0 WGs + 64 layer-1 WGs
#define R_ 16        // h ring slots (power of 2)

typedef __attribute__((ext_vector_type(8))) short short8;
typedef __attribute__((ext_vector_type(4))) float f32x4;

__device__ __forceinline__ unsigned short f2bf(float f) {
  union { float f; unsigned u; } v; v.f = f;
  return (unsigned short)((v.u + 0x7fffu + ((v.u >> 16) & 1u)) >> 16);
}
__device__ __forceinline__ float bf2f(unsigned short s) {
  union { unsigned u; float f; } v; v.u = ((unsigned)s) << 16; return v.f;
}
__device__ __forceinline__ float sigmoidf_(float x) { return 1.f / (1.f + __expf(-x)); }
__device__ __forceinline__ float tanhf_(float x) { return 1.f - 2.f / (__expf(2.f * x) + 1.f); }

__device__ __forceinline__ float ldx(const float* p) { return *p; }
__device__ __forceinline__ float ldx(const unsigned short* p) { return bf2f(*p); }
__device__ __forceinline__ void stc(float* p, float v) { *p = v; }
__device__ __forceinline__ void stc(unsigned short* p, float v) { *p = f2bf(v); }

// coherent (LLC) accesses -- relaxed agent scope, no cache-maintenance side effects
__device__ __forceinline__ unsigned cohload_u32(const unsigned* p) {
  return __hip_atomic_load(p, __ATOMIC_RELAXED, __HIP_MEMORY_SCOPE_AGENT);
}
__device__ __forceinline__ void cohstore_u32(unsigned* p, unsigned v) {
  __hip_atomic_store(p, v, __ATOMIC_RELAXED, __HIP_MEMORY_SCOPE_AGENT);
}
__device__ __forceinline__ int cohload_i32(const int* p) {
  return __hip_atomic_load(p, __ATOMIC_RELAXED, __HIP_MEMORY_SCOPE_AGENT);
}
__device__ __forceinline__ void cohstore_i32(int* p, int v) {
  __hip_atomic_store(p, v, __ATOMIC_RELAXED, __HIP_MEMORY_SCOPE_AGENT);
}

// ---------------- converts ----------------
__global__ void k_convert_x(const float* __restrict__ x, unsigned short* __restrict__ xT) {
  const int nq = T_ * B_ * DIN / 4;
  for (int q = blockIdx.x * blockDim.x + threadIdx.x; q < nq; q += gridDim.x * blockDim.x) {
    int e = q * 4;
    int d = e % DIN;
    int row = e / DIN;            // t*B + b
    int b = row & (B_ - 1), t = row / B_;
    float4 v = *(const float4*)(x + ((size_t)b * T_ + t) * DIN + d);
    unsigned short o[4] = { f2bf(v.x), f2bf(v.y), f2bf(v.z), f2bf(v.w) };
    *(uint2*)(xT + (size_t)row * DIN + d) = *(const uint2*)o;
  }
}

__global__ void k_convert_w(const float* __restrict__ w, unsigned short* __restrict__ o, int n) {
  const int nq = n / 4;
  for (int q = blockIdx.x * blockDim.x + threadIdx.x; q < nq; q += gridDim.x * blockDim.x) {
    float4 v = *(const float4*)(w + q * 4);
    unsigned short s[4] = { f2bf(v.x), f2bf(v.y), f2bf(v.z), f2bf(v.w) };
    *(uint2*)(o + q * 4) = *(const uint2*)s;
  }
}

// ---------------- GEMM: C[M,2048] = A[M,K](bf16) @ W[2048,K]^T(bf16) + (ba+bb) ----------------
template <typename XGT>
__global__ __launch_bounds__(256, 1) void k_gemm_bias(
    const unsigned short* __restrict__ A, const unsigned short* __restrict__ Bw,
    const float* __restrict__ ba, const float* __restrict__ bb,
    XGT* __restrict__ C, int K, int ntn) {
  __shared__ unsigned short lds[16384];
  const int bid = blockIdx.x;
  const int nt = bid % ntn, mt = bid / ntn;
  const int tid = threadIdx.x;
  const int lane = tid & 63, wv = tid >> 6;
  const int wm = wv & 1, wn = wv >> 1;
  f32x4 acc[4][4] = {};
  const int nkt = K >> 6;
  const size_t ar0 = (size_t)mt * 128, br0 = (size_t)nt * 128;
  for (int kt = 0; kt < nkt; ++kt) {
    __syncthreads();
#pragma unroll
    for (int jj = 0; jj < 4; ++jj) {
      int g = tid + jj * 256;
      int row = g >> 3, gc = g & 7;
      int dst = (((row >> 4) * 2 + (gc >> 2)) * 64 + ((row & 15) + ((gc & 3) << 4))) * 8;
      uint4 va = *(const uint4*)(A + (ar0 + row) * (size_t)K + (size_t)kt * 64 + gc * 8);
      *(uint4*)&lds[dst] = va;
      uint4 vb = *(const uint4*)(Bw + (br0 + row) * (size_t)K + (size_t)kt * 64 + gc * 8);
      *(uint4*)&lds[8192 + dst] = vb;
    }
    __syncthreads();
#pragma unroll
    for (int kk = 0; kk < 2; ++kk) {
      short8 af[4], bf[4];
#pragma unroll
      for (int m = 0; m < 4; ++m)
        af[m] = *(const short8*)&lds[(((wm * 4 + m) * 2 + kk) * 64 + lane) * 8];
#pragma unroll
      for (int n = 0; n < 4; ++n)
        bf[n] = *(const short8*)&lds[8192 + (((wn * 4 + n) * 2 + kk) * 64 + lane) * 8];
#pragma unroll
      for (int m = 0; m < 4; ++m)
#pragma unroll
        for (int n = 0; n < 4; ++n)
          acc[m][n] = __builtin_amdgcn_mfma_f32_16x16x32_bf16(af[m], bf[n], acc[m][n], 0, 0, 0);
    }
  }
#pragma unroll
  for (int n = 0; n < 4; ++n) {
    int col = (int)br0 + wn * 64 + n * 16 + (lane & 15);
    float bsum = ba[col] + bb[col];
#pragma unroll
    for (int m = 0; m < 4; ++m) {
      size_t row = ar0 + wm * 64 + m * 16 + ((lane >> 4) * 4);
#pragma unroll
      for (int r = 0; r < 4; ++r)
        stc(C + (row + r) * G4 + col, acc[m][n][r] + bsum);
    }
  }
}

// ---------------- tagged-ring staging: poll tags, extract bf16, write swizzled LDS ----------------
// ring element u32 = (bf16 << 16) | tag. Stages one 32-batch half (64KB of u32) into hbuf.
__device__ __forceinline__ void stage_ring(const unsigned* __restrict__ ring, int slot, int bh,
                                           int tid, unsigned exp, unsigned short* __restrict__ hbuf) {
  const unsigned* base = ring + ((size_t)slot * B_ + bh * 32) * H_;
#pragma unroll
  for (int j = 0; j < 8; ++j) {
    int ch = tid + j * 256;
    int b = ch >> 6, g = ch & 63;                 // row (local batch), 8-elem granule
    const unsigned* src = base + (size_t)b * H_ + g * 8;
    unsigned q[8];
    for (;;) {
      int ok = 1;
#pragma unroll
      for (int i = 0; i < 8; ++i) {
        q[i] = cohload_u32(src + i);
        ok &= ((q[i] & 0xFFFFu) == exp) ? 1 : 0;
      }
      if (__all(ok)) break;
      __builtin_amdgcn_s_sleep(1);
    }
    unsigned p[4];
#pragma unroll
    for (int i = 0; i < 4; ++i)
      p[i] = (q[2 * i] >> 16) | (q[2 * i + 1] & 0xFFFF0000u);
    *(uint4*)&hbuf[g * 256 + (b ^ (g & 7)) * 8] = *(const uint4*)p;
  }
}

// ---------------- fused 2-layer persistent LSTM (v5: tagged fire-and-forget protocol) ----------------
// 128 WGs x 4 waves. WGs 0..63 = layer 0, 64..127 = layer 1. WG (cg,bh): h-cols
// [cg*16,+16), batches [bh*32,+32). Producers fire tagged u32 stores (atomic dword =
// value+tag publish together) -- no vmcnt drain, no release fence. prog flags are
// HINTS only; tags carry correctness. cons1 (published after the post-staging
// barrier) gives L0 back-pressure so ring slots are never reused before consumption.
template <typename XGT>
__global__ __launch_bounds__(256, 1) void k_lstm5(
    const XGT* __restrict__ xg0,         // [T,B,4H] layer-0 input gates
    const float* __restrict__ whh0, const float* __restrict__ wih1,
    const float* __restrict__ whh1,
    const float* __restrict__ bih1, const float* __restrict__ bhh1,
    unsigned* __restrict__ h0r,          // [R_,B,H] tagged ring
    unsigned* __restrict__ h1r,          // [R_,B,H] tagged ring
    int* __restrict__ prog0, int* __restrict__ prog1, int* __restrict__ cons1) {
  __shared__ unsigned short hbufA[32 * 512];   // 32KB swizzled: elem g*256+(b^(g&7))*8
  __shared__ unsigned short hbufB[32 * 512];   // 32KB (layer 1 only)
  __shared__ float gbuf[8 * 64 * 5];           // 10KB gate exchange
  const int wgid = blockIdx.x;
  const int wg2 = wgid & 63;
  const int cg = wg2 >> 1, bh = wg2 & 1;
  const int tid = threadIdx.x;
  const int lane = tid & 63, wv = tid >> 6;
  const int l15 = lane & 15, l4 = lane >> 4;
  const int um = wv >> 1, rb = (wv & 1) * 2;
  const int fidx = (lane & 31) * 2 + bh;

  if (wgid < 64) {
    // ================= LAYER 0 =================
    short8 wreg[16];
    {
      const float* wrow = whh0 + ((size_t)wv * H_ + cg * 16 + l15) * H_ + l4 * 8;
#pragma unroll
      for (int kk = 0; kk < 16; ++kk) {
        float4 v0 = *(const float4*)(wrow + kk * 32);
        float4 v1 = *(const float4*)(wrow + kk * 32 + 4);
        unsigned short o[8] = { f2bf(v0.x), f2bf(v0.y), f2bf(v0.z), f2bf(v0.w),
                                f2bf(v1.x), f2bf(v1.y), f2bf(v1.z), f2bf(v1.w) };
        wreg[kk] = *(const short8*)o;
      }
    }
    float c2[2] = {0.f, 0.f};

    for (int t = 0; t < T_; ++t) {
      float xr[2][4];
      {
        const XGT* xb = xg0 + ((size_t)t * B_ + bh * 32 + um * 16 + l4 * 4 + rb) * (size_t)G4 + cg * 16 + l15;
#pragma unroll
        for (int rr = 0; rr < 2; ++rr)
#pragma unroll
          for (int s = 0; s < 4; ++s)
            xr[rr][s] = ldx(xb + (size_t)rr * G4 + s * H_);
      }
      if (t > 0) {
        // hint: peers published h0(t-1)
        for (;;) {
          int v = (lane < 32) ? cohload_i32(prog0 + fidx) : 0x7fffffff;
          if (__all(v >= t)) break;
          __builtin_amdgcn_s_sleep(1);
        }
        stage_ring(h0r, (t - 1) & (R_ - 1), bh, tid, (unsigned)t, hbufA);
      }
      if (t >= R_) {
        // back-pressure: all L1 consumers of my half finished staging h0(t-R_)
        for (;;) {
          int v = (lane < 32) ? cohload_i32(cons1 + fidx) : 0x7fffffff;
          if (__all(v >= t - R_ + 1)) break;
          __builtin_amdgcn_s_sleep(2);
        }
      }
      __syncthreads();

      f32x4 acc[2];
      {
        f32x4 aE[2] = {}, aO[2] = {};
        if (t > 0) {
#pragma unroll
          for (int kk = 0; kk < 16; kk += 2) {
            int g0 = kk * 4 + l4, g1 = (kk + 1) * 4 + l4;
            int e0 = g0 * 256 + (l15 ^ (g0 & 7)) * 8;
            int e1 = g1 * 256 + (l15 ^ (g1 & 7)) * 8;
            short8 x0 = *(const short8*)&hbufA[e0];
            short8 x1 = *(const short8*)&hbufA[e0 + 128];
            short8 y0 = *(const short8*)&hbufA[e1];
            short8 y1 = *(const short8*)&hbufA[e1 + 128];
            aE[0] = __builtin_amdgcn_mfma_f32_16x16x32_bf16(x0, wreg[kk], aE[0], 0, 0, 0);
            aE[1] = __builtin_amdgcn_mfma_f32_16x16x32_bf16(x1, wreg[kk], aE[1], 0, 0, 0);
            aO[0] = __builtin_amdgcn_mfma_f32_16x16x32_bf16(y0, wreg[kk + 1], aO[0], 0, 0, 0);
            aO[1] = __builtin_amdgcn_mfma_f32_16x16x32_bf16(y1, wreg[kk + 1], aO[1], 0, 0, 0);
          }
        }
        acc[0] = aE[0] + aO[0];
        acc[1] = aE[1] + aO[1];
      }

#pragma unroll
      for (int m = 0; m < 2; ++m)
#pragma unroll
        for (int r = 0; r < 4; ++r)
          gbuf[((wv * 2 + m) * 64 + lane) * 5 + r] = acc[m][r];
      __syncthreads();

      unsigned* hw = h0r + ((size_t)(t & (R_ - 1)) * B_ + bh * 32) * H_ + cg * 16 + l15;
      const unsigned tag = (unsigned)(t + 1);
#pragma unroll
      for (int rr = 0; rr < 2; ++rr) {
        int r = rb + rr;
        float g4v[4];
#pragma unroll
        for (int s = 0; s < 4; ++s)
          g4v[s] = gbuf[((s * 2 + um) * 64 + lane) * 5 + r] + xr[rr][s];
        float iv = sigmoidf_(g4v[0]);
        float fv = sigmoidf_(g4v[1]);
        float gv = tanhf_(g4v[2]);
        float ov = sigmoidf_(g4v[3]);
        float cn = fv * c2[rr] + iv * gv;
        c2[rr] = cn;
        unsigned enc = (((unsigned)f2bf(ov * tanhf_(cn))) << 16) | tag;
        cohstore_u32(hw + (size_t)(um * 16 + l4 * 4 + r) * H_, enc);
      }
      if (tid == 0) cohstore_i32(prog0 + wg2, t + 1);
    }
  } else {
    // ================= LAYER 1 =================
    short8 wregA[16], wregB[16];
    {
      const float* wrA = wih1 + ((size_t)wv * H_ + cg * 16 + l15) * H_ + l4 * 8;
      const float* wrB = whh1 + ((size_t)wv * H_ + cg * 16 + l15) * H_ + l4 * 8;
#pragma unroll
      for (int kk = 0; kk < 16; ++kk) {
        float4 a0 = *(const float4*)(wrA + kk * 32);
        float4 a1 = *(const float4*)(wrA + kk * 32 + 4);
        unsigned short oa[8] = { f2bf(a0.x), f2bf(a0.y), f2bf(a0.z), f2bf(a0.w),
                                 f2bf(a1.x), f2bf(a1.y), f2bf(a1.z), f2bf(a1.w) };
        wregA[kk] = *(const short8*)oa;
        float4 b0 = *(const float4*)(wrB + kk * 32);
        float4 b1 = *(const float4*)(wrB + kk * 32 + 4);
        unsigned short ob[8] = { f2bf(b0.x), f2bf(b0.y), f2bf(b0.z), f2bf(b0.w),
                                 f2bf(b1.x), f2bf(b1.y), f2bf(b1.z), f2bf(b1.w) };
        wregB[kk] = *(const short8*)ob;
      }
    }
    float b1s[4];
    {
      int col = cg * 16 + l15;
#pragma unroll
      for (int s = 0; s < 4; ++s) b1s[s] = bih1[s * H_ + col] + bhh1[s * H_ + col];
    }
    float c2[2] = {0.f, 0.f};

    for (int t = 0; t < T_; ++t) {
      // hint: h0(t) published (prog0 >= t+1) and peers' h1(t-1) published (prog1 >= t)
      {
        const int* fp = (lane < 32) ? prog0 : prog1;
        const int need = (lane < 32) ? (t + 1) : t;
        for (;;) {
          int v = cohload_i32(fp + fidx);
          if (__all(v >= need)) break;
          __builtin_amdgcn_s_sleep(1);
        }
      }
      stage_ring(h0r, t & (R_ - 1), bh, tid, (unsigned)(t + 1), hbufA);
      if (t > 0)
        stage_ring(h1r, (t - 1) & (R_ - 1), bh, tid, (unsigned)t, hbufB);
      __syncthreads();
      // publish h0(t) consumption AFTER the barrier (all threads provably staged)
      if (tid == 0) cohstore_i32(cons1 + wg2, t + 1);

      f32x4 acc[2];
      {
        f32x4 aA[2] = {}, aB[2] = {};
#pragma unroll
        for (int kk = 0; kk < 16; ++kk) {
          int g = kk * 4 + l4;
          int e = g * 256 + (l15 ^ (g & 7)) * 8;
          short8 a0 = *(const short8*)&hbufA[e];
          short8 a1 = *(const short8*)&hbufA[e + 128];
          aA[0] = __builtin_amdgcn_mfma_f32_16x16x32_bf16(a0, wregA[kk], aA[0], 0, 0, 0);
          aA[1] = __builtin_amdgcn_mfma_f32_16x16x32_bf16(a1, wregA[kk], aA[1], 0, 0, 0);
          if (t > 0) {
            short8 b0 = *(const short8*)&hbufB[e];
            short8 b1v = *(const short8*)&hbufB[e + 128];
            aB[0] = __builtin_amdgcn_mfma_f32_16x16x32_bf16(b0, wregB[kk], aB[0], 0, 0, 0);
            aB[1] = __builtin_amdgcn_mfma_f32_16x16x32_bf16(b1v, wregB[kk], aB[1], 0, 0, 0);
          }
        }
        acc[0] = aA[0] + aB[0];
        acc[1] = aA[1] + aB[1];
      }

#pragma unroll
      for (int m = 0; m < 2; ++m)
#pragma unroll
        for (int r = 0; r < 4; ++r)
          gbuf[((wv * 2 + m) * 64 + lane) * 5 + r] = acc[m][r];
      __syncthreads();

      unsigned* hw = h1r + ((size_t)(t & (R_ - 1)) * B_ + bh * 32) * H_ + cg * 16 + l15;
      const unsigned tag = (unsigned)(t + 1);
#pragma unroll
      for (int rr = 0; rr < 2; ++rr) {
        int r = rb + rr;
        float g4v[4];
#pragma unroll
        for (int s = 0; s < 4; ++s)
          g4v[s] = gbuf[((s * 2 + um) * 64 + lane) * 5 + r] + b1s[s];
        float iv = sigmoidf_(g4v[0]);
        float fv = sigmoidf_(g4v[1]);
        float gv = tanhf_(g4v[2]);
        float ov = sigmoidf_(g4v[3]);
        float cn = fv * c2[rr] + iv * gv;
        c2[rr] = cn;
        unsigned enc = (((unsigned)f2bf(ov * tanhf_(cn))) << 16) | tag;
        cohstore_u32(hw + (size_t)(um * 16 + l4 * 4 + r) * H_, enc);
      }
      if (tid == 0) cohstore_i32(prog1 + wg2, t + 1);
    }
  }
}

// ---------------- final FC + sigmoid (reads tagged ring slot) ----------------
__global__ void k_fc(const unsigned* __restrict__ hring, const float* __restrict__ w,
                     const float* __restrict__ bfc, float* __restrict__ out) {
  int b = threadIdx.x;
  if (b < B_) {
    const unsigned* hb = hring + ((size_t)((T_ - 1) & (R_ - 1)) * B_ + b) * H_;
    float s = 0.f;
    for (int j = 0; j < H_; ++j) s += bf2f((unsigned short)(hb[j] >> 16)) * w[j];
    out[b] = sigmoidf_(s + bfc[0]);
  }
}

extern "C" void kernel_launch(void* const* d_in, const int* in_sizes, int n_in,
                              void* d_out, int out_size, void* d_ws, size_t ws_size,
                              hipStream_t stream) {
  (void)in_sizes; (void)n_in; (void)out_size;
  const float* x    = (const float*)d_in[0];
  const float* wih0 = (const float*)d_in[1];
  const float* whh0 = (const float*)d_in[2];
  const float* bih0 = (const float*)d_in[3];
  const float* bhh0 = (const float*)d_in[4];
  const float* wih1 = (const float*)d_in[5];
  const float* whh1 = (const float*)d_in[6];
  const float* bih1 = (const float*)d_in[7];
  const float* bhh1 = (const float*)d_in[8];
  const float* wfc  = (const float*)d_in[9];
  const float* bfc  = (const float*)d_in[10];
  float* out = (float*)d_out;

  const size_t ring_ints = (size_t)R_ * B_ * H_;   // 524288 u32 = 2MB
  char* ws = (char*)d_ws;
  int* prog0 = (int*)ws;                    // 64 ints
  int* prog1 = prog0 + 64;                  // 64 ints
  int* cons1 = prog0 + 128;                 // 64 ints
  size_t off = 4096;
  unsigned* h0r = (unsigned*)(ws + off);    off += ring_ints * 4;   // 2MB
  unsigned* h1r = (unsigned*)(ws + off);    off += ring_ints * 4;   // 2MB
  unsigned short* xT = (unsigned short*)(ws + off);    off += (size_t)T_ * B_ * DIN * 2;
  unsigned short* wih0b = (unsigned short*)(ws + off); off += (size_t)G4 * DIN * 2;
  size_t xg_off = off;
  const size_t need_f32 = xg_off + (size_t)T_ * B_ * G4 * 4;

  const int gemm_grid = (T_ * B_ / 128) * (G4 / 128);
  const int ntn = G4 / 128;

  // clear flags + rings (stale tags from a previous replay would alias this run's tags)
  hipMemsetAsync(ws, 0, 4096 + ring_ints * 8, stream);
  k_convert_x<<<2048, 256, 0, stream>>>(x, xT);
  k_convert_w<<<512, 256, 0, stream>>>(wih0, wih0b, G4 * DIN);

  if (ws_size >= need_f32) {
    float* xgbuf = (float*)(ws + xg_off);
    k_gemm_bias<float><<<gemm_grid, 256, 0, stream>>>(xT, wih0b, bih0, bhh0, xgbuf, DIN, ntn);
    k_lstm5<float><<<NWGF, 256, 0, stream>>>(xgbuf, whh0, wih1, whh1, bih1, bhh1,
                                             h0r, h1r, prog0, prog1, cons1);
  } else {
    unsigned short* xgbuf = (unsigned short*)(ws + xg_off);
    k_gemm_bias<unsigned short><<<gemm_grid, 256, 0, stream>>>(xT, wih0b, bih0, bhh0, xgbuf, DIN, ntn);
    k_lstm5<unsigned short><<<NWGF, 256, 0, stream>>>(xgbuf, whh0, wih1, whh1, bih1, bhh1,
                                                      h0r, h1r, prog0, prog1, cons1);
  }
  k_fc<<<1, 64, 0, stream>>>(h1r, wfc, bfc, out);
}

// Round 6
// 3433.089 us; speedup vs baseline: 2.6395x; 2.6395x over previous
//
#include <hip/hip_runtime.h>
#include <stdint.h>
#include <stddef.h>

#define B_ 64
#define T_ 512
#define DIN 256
#define H_ 512

typedef __attribute__((ext_vector_type(8))) short short8;
typedef __attribute__((ext_vector_type(4))) float f32x4;

__device__ __forceinline__ unsigned short f2bf(float f) {
  union { float f; unsigned u; } v; v.f = f;
  return (unsigned short)((v.u + 0x7fffu + ((v.u >> 16) & 1u)) >> 16);
}
__device__ __forceinline__ float bf2f(unsigned short s) {
  union { unsigned u; float f; } v; v.u = ((unsigned)s) << 16; return v.f;
}
__device__ __forceinline__ float sigmoidf_(float x) { return 1.f / (1.f + __expf(-x)); }
__device__ __forceinline__ float tanhf_(float x) { return 1.f - 2.f / (__expf(2.f * x) + 1.f); }

// coherent (LLC, sc0|sc1) accesses -- no cache-maintenance side effects
__device__ __forceinline__ unsigned long long cohload_u64(const unsigned long long* p) {
  return __hip_atomic_load(p, __ATOMIC_RELAXED, __HIP_MEMORY_SCOPE_AGENT);
}
__device__ __forceinline__ void cohstore_u64(unsigned long long* p, unsigned long long v) {
  __hip_atomic_store(p, v, __ATOMIC_RELAXED, __HIP_MEMORY_SCOPE_AGENT);
}
__device__ __forceinline__ int cohload_i32(const int* p) {
  return __hip_atomic_load(p, __ATOMIC_RELAXED, __HIP_MEMORY_SCOPE_AGENT);
}
__device__ __forceinline__ void cohstore_i32(int* p, int v) {
  __hip_atomic_store(p, v, __ATOMIC_RELAXED, __HIP_MEMORY_SCOPE_AGENT);
}

// any u16 lane == 0 ? (borrow trick; detection of lowest zero lane is guaranteed)
__device__ __forceinline__ int haszero16(unsigned long long x) {
  return ((x - 0x0001000100010001ULL) & ~x & 0x8000800080008000ULL) != 0ULL;
}

// ---------------- convert: x [B,T,DIN] f32 -> xT [T,B,DIN] bf16 ----------------
__global__ void k_convert_x(const float* __restrict__ x, unsigned short* __restrict__ xT) {
  const int nq = T_ * B_ * DIN / 4;
  for (int q = blockIdx.x * blockDim.x + threadIdx.x; q < nq; q += gridDim.x * blockDim.x) {
    int e = q * 4;
    int d = e % DIN;
    int row = e / DIN;            // t*B + b
    int b = row & (B_ - 1), t = row / B_;
    float4 v = *(const float4*)(x + ((size_t)b * T_ + t) * DIN + d);
    unsigned short o[4] = { f2bf(v.x), f2bf(v.y), f2bf(v.z), f2bf(v.w) };
    *(uint2*)(xT + (size_t)row * DIN + d) = *(const uint2*)o;
  }
}

// stage one 16-batch slice (16KB, encoded u16) into swizzled LDS, verifying freshness.
// Layout: elem = g*128 + ((b ^ (g&15))*8), granule g = 16B of 8 cols.
__device__ __forceinline__ void stage_h(const unsigned short* __restrict__ base,
                                        int tid, unsigned short* __restrict__ dst) {
  const unsigned long long* s64 = (const unsigned long long*)base;
  unsigned long long q[8];
#pragma unroll
  for (int j = 0; j < 4; ++j) {
    size_t o = (size_t)(tid + j * 256) * 2;
    q[2 * j] = cohload_u64(s64 + o);
    q[2 * j + 1] = cohload_u64(s64 + o + 1);
  }
#pragma unroll
  for (int j = 0; j < 4; ++j) {
    int ch = tid + j * 256;
    const unsigned long long* p = s64 + (size_t)ch * 2;
    while (haszero16(q[2 * j]) || haszero16(q[2 * j + 1])) {
      q[2 * j] = cohload_u64(p); q[2 * j + 1] = cohload_u64(p + 1);
    }
    int b = ch >> 6, g = ch & 63;
    unsigned long long dd[2] = { q[2 * j] - 0x0001000100010001ULL,
                                 q[2 * j + 1] - 0x0001000100010001ULL };
    *(uint4*)&dst[g * 128 + ((b ^ (g & 15)) * 8)] = *(const uint4*)dd;
  }
}

// stage TWO slices with all 16 loads in flight before verification
__device__ __forceinline__ void stage_h2(const unsigned short* __restrict__ baseA,
                                         const unsigned short* __restrict__ baseB,
                                         int tid, unsigned short* __restrict__ dstA,
                                         unsigned short* __restrict__ dstB) {
  const unsigned long long* sA = (const unsigned long long*)baseA;
  const unsigned long long* sB = (const unsigned long long*)baseB;
  unsigned long long q[16];
#pragma unroll
  for (int j = 0; j < 4; ++j) {
    size_t o = (size_t)(tid + j * 256) * 2;
    q[2 * j] = cohload_u64(sA + o);     q[2 * j + 1] = cohload_u64(sA + o + 1);
    q[8 + 2 * j] = cohload_u64(sB + o); q[8 + 2 * j + 1] = cohload_u64(sB + o + 1);
  }
#pragma unroll
  for (int j = 0; j < 4; ++j) {
    int ch = tid + j * 256;
    int b = ch >> 6, g = ch & 63;
    int el = g * 128 + ((b ^ (g & 15)) * 8);
    const unsigned long long* pA = sA + (size_t)ch * 2;
    while (haszero16(q[2 * j]) || haszero16(q[2 * j + 1])) {
      q[2 * j] = cohload_u64(pA); q[2 * j + 1] = cohload_u64(pA + 1);
    }
    unsigned long long da[2] = { q[2 * j] - 0x0001000100010001ULL,
                                 q[2 * j + 1] - 0x0001000100010001ULL };
    *(uint4*)&dstA[el] = *(const uint4*)da;
    const unsigned long long* pB = sB + (size_t)ch * 2;
    while (haszero16(q[8 + 2 * j]) || haszero16(q[8 + 2 * j + 1])) {
      q[8 + 2 * j] = cohload_u64(pB); q[8 + 2 * j + 1] = cohload_u64(pB + 1);
    }
    unsigned long long db[2] = { q[8 + 2 * j] - 0x0001000100010001ULL,
                                 q[8 + 2 * j + 1] - 0x0001000100010001ULL };
    *(uint4*)&dstB[el] = *(const uint4*)db;
  }
}

// ---------------- fused 2-layer persistent LSTM (v6) ----------------
// 256 WGs x 4 waves (1 per CU). WGs [0,128)=layer0, [128,256)=layer1.
// WG (cg,bh): h-cols [cg*16,+16), batches [bh*16,+16). Wave wv computes gate
// section wv. L0 computes W_ih0@x(t) on the fly (no xg GEMM); x tiles double-
// buffered + prefetched. h stored encoded (bf16+1, never 0) via relaxed LLC
// atomics; flags are hints only; zero-lane verification carries correctness.
__global__ __launch_bounds__(256, 1) void k_lstm6(
    const unsigned short* __restrict__ xT,   // [T,B,DIN] bf16
    const float* __restrict__ wih0, const float* __restrict__ whh0,
    const float* __restrict__ bih0, const float* __restrict__ bhh0,
    const float* __restrict__ wih1, const float* __restrict__ whh1,
    const float* __restrict__ bih1, const float* __restrict__ bhh1,
    unsigned short* __restrict__ h0, unsigned short* __restrict__ h1,  // [T,B,H] encoded
    int* __restrict__ prog0, int* __restrict__ prog1) {
  __shared__ unsigned short hbufA[8192];   // 16KB swizzled h tile
  __shared__ unsigned short bufX[8192];    // 16KB: L0 = x dbuf [2][4096]; L1 = hbufB
  __shared__ float gbuf[4 * 64 * 5];       // 5KB gate exchange (stride-5)
  __shared__ unsigned short hstage[16 * 20];
  const int wgid = blockIdx.x;
  const int layer = wgid >> 7;
  const int wg2 = wgid & 127;
  const int cg = wg2 >> 2, bh = wg2 & 3;
  const int tid = threadIdx.x;
  const int lane = tid & 63, wv = tid >> 6;
  const int l15 = lane & 15, l4 = lane >> 4;
  const int colb = cg * 16, bb = bh * 16;
  const int ucol = tid & 15, ubat = tid >> 4;
  const int lp = (ubat >> 2) * 16 + ucol, ur = ubat & 3;

  if (layer == 0) {
    // ---- weights -> VGPR ----
    short8 wih[8], whh[16];
    {
      const float* wr = wih0 + (size_t)(wv * H_ + colb + l15) * DIN + l4 * 8;
#pragma unroll
      for (int kk = 0; kk < 8; ++kk) {
        float4 v0 = *(const float4*)(wr + kk * 32);
        float4 v1 = *(const float4*)(wr + kk * 32 + 4);
        unsigned short o[8] = { f2bf(v0.x), f2bf(v0.y), f2bf(v0.z), f2bf(v0.w),
                                f2bf(v1.x), f2bf(v1.y), f2bf(v1.z), f2bf(v1.w) };
        wih[kk] = *(const short8*)o;
      }
      const float* wr2 = whh0 + (size_t)(wv * H_ + colb + l15) * H_ + l4 * 8;
#pragma unroll
      for (int kk = 0; kk < 16; ++kk) {
        float4 v0 = *(const float4*)(wr2 + kk * 32);
        float4 v1 = *(const float4*)(wr2 + kk * 32 + 4);
        unsigned short o[8] = { f2bf(v0.x), f2bf(v0.y), f2bf(v0.z), f2bf(v0.w),
                                f2bf(v1.x), f2bf(v1.y), f2bf(v1.z), f2bf(v1.w) };
        whh[kk] = *(const short8*)o;
      }
    }
    float b0s[4];
#pragma unroll
    for (int s = 0; s < 4; ++s)
      b0s[s] = bih0[s * H_ + colb + ucol] + bhh0[s * H_ + colb + ucol];
    float cst = 0.f;

    // prologue: stage x(0) into bufX[0]
    {
      int b0c = tid >> 5, g0c = tid & 31, b1c = (tid + 256) >> 5, g1c = tid & 31;
      uint4 v0 = *(const uint4*)(xT + (size_t)(bb + b0c) * DIN + g0c * 8);
      uint4 v1 = *(const uint4*)(xT + (size_t)(bb + b1c) * DIN + g1c * 8);
      *(uint4*)&bufX[g0c * 128 + ((b0c ^ (g0c & 15)) * 8)] = v0;
      *(uint4*)&bufX[g1c * 128 + ((b1c ^ (g1c & 15)) * 8)] = v1;
    }
    __syncthreads();

    for (int t = 0; t < T_; ++t) {
      unsigned short* xb = bufX + (t & 1) * 4096;
      // x-part MFMAs (data staged last tick)
      f32x4 accE = {}, accO = {};
#pragma unroll
      for (int kk = 0; kk < 8; ++kk) {
        int g = kk * 4 + l4;
        short8 a = *(const short8*)&xb[g * 128 + ((l15 ^ (g & 15)) * 8)];
        accE = __builtin_amdgcn_mfma_f32_16x16x32_bf16(a, wih[kk], accE, 0, 0, 0);
      }
      // prefetch x(t+1)
      uint4 xv0, xv1;
      const bool hasx = (t + 1 < T_);
      if (hasx) {
        int b0c = tid >> 5, g0c = tid & 31, b1c = (tid + 256) >> 5;
        const unsigned short* xs = xT + (size_t)(t + 1) * (B_ * DIN);
        xv0 = *(const uint4*)(xs + (size_t)(bb + b0c) * DIN + g0c * 8);
        xv1 = *(const uint4*)(xs + (size_t)(bb + b1c) * DIN + g0c * 8);
      }
      if (t > 0) {
        for (;;) {
          int v = (lane < 32) ? cohload_i32(prog0 + (lane * 4 + bh)) : 0x7fffffff;
          if (__all(v >= t)) break;
        }
        stage_h(h0 + ((size_t)(t - 1) * B_ + bb) * H_, tid, hbufA);
      }
      if (hasx) {
        unsigned short* xd = bufX + ((t + 1) & 1) * 4096;
        int b0c = tid >> 5, g0c = tid & 31, b1c = (tid + 256) >> 5;
        *(uint4*)&xd[g0c * 128 + ((b0c ^ (g0c & 15)) * 8)] = xv0;
        *(uint4*)&xd[g0c * 128 + ((b1c ^ (g0c & 15)) * 8)] = xv1;
      }
      __syncthreads();
      if (t > 0) {
#pragma unroll
        for (int kk = 0; kk < 16; kk += 2) {
          int g0 = kk * 4 + l4, g1 = (kk + 1) * 4 + l4;
          short8 a0 = *(const short8*)&hbufA[g0 * 128 + ((l15 ^ (g0 & 15)) * 8)];
          short8 a1 = *(const short8*)&hbufA[g1 * 128 + ((l15 ^ (g1 & 15)) * 8)];
          accE = __builtin_amdgcn_mfma_f32_16x16x32_bf16(a0, whh[kk], accE, 0, 0, 0);
          accO = __builtin_amdgcn_mfma_f32_16x16x32_bf16(a1, whh[kk + 1], accO, 0, 0, 0);
        }
      }
      f32x4 acc = accE + accO;
#pragma unroll
      for (int r = 0; r < 4; ++r) gbuf[(wv * 64 + lane) * 5 + r] = acc[r];
      __syncthreads();
      {
        float g4[4];
#pragma unroll
        for (int s = 0; s < 4; ++s) g4[s] = gbuf[(s * 64 + lp) * 5 + ur] + b0s[s];
        float iv = sigmoidf_(g4[0]), fv = sigmoidf_(g4[1]);
        float gv = tanhf_(g4[2]), ov = sigmoidf_(g4[3]);
        cst = fv * cst + iv * gv;
        hstage[ubat * 20 + ucol] = (unsigned short)(f2bf(ov * tanhf_(cst)) + 1);
      }
      __syncthreads();
      if (tid < 64) {
        int bl = tid >> 2, q = tid & 3;
        unsigned long long v = *(const unsigned long long*)&hstage[bl * 20 + q * 4];
        cohstore_u64((unsigned long long*)(h0 + ((size_t)t * B_ + bb + bl) * H_ + colb) + q, v);
      }
      if (tid == 0) cohstore_i32(prog0 + wg2, t + 1);
    }
  } else {
    // ================= LAYER 1 =================
    short8 wA[16], wB[16];
    {
      const float* wrA = wih1 + (size_t)(wv * H_ + colb + l15) * H_ + l4 * 8;
      const float* wrB = whh1 + (size_t)(wv * H_ + colb + l15) * H_ + l4 * 8;
#pragma unroll
      for (int kk = 0; kk < 16; ++kk) {
        float4 a0 = *(const float4*)(wrA + kk * 32);
        float4 a1 = *(const float4*)(wrA + kk * 32 + 4);
        unsigned short oa[8] = { f2bf(a0.x), f2bf(a0.y), f2bf(a0.z), f2bf(a0.w),
                                 f2bf(a1.x), f2bf(a1.y), f2bf(a1.z), f2bf(a1.w) };
        wA[kk] = *(const short8*)oa;
        float4 b0 = *(const float4*)(wrB + kk * 32);
        float4 b1 = *(const float4*)(wrB + kk * 32 + 4);
        unsigned short ob[8] = { f2bf(b0.x), f2bf(b0.y), f2bf(b0.z), f2bf(b0.w),
                                 f2bf(b1.x), f2bf(b1.y), f2bf(b1.z), f2bf(b1.w) };
        wB[kk] = *(const short8*)ob;
      }
    }
    float b1s[4];
#pragma unroll
    for (int s = 0; s < 4; ++s)
      b1s[s] = bih1[s * H_ + colb + ucol] + bhh1[s * H_ + colb + ucol];
    float cst = 0.f;

    for (int t = 0; t < T_; ++t) {
      for (;;) {
        const int* fp = (lane < 32) ? prog0 : prog1;
        const int need = (lane < 32) ? (t + 1) : t;
        int v = cohload_i32(fp + ((lane & 31) * 4 + bh));
        if (__all(v >= need)) break;
      }
      if (t > 0)
        stage_h2(h0 + ((size_t)t * B_ + bb) * H_, h1 + ((size_t)(t - 1) * B_ + bb) * H_,
                 tid, hbufA, bufX);
      else
        stage_h(h0 + ((size_t)t * B_ + bb) * H_, tid, hbufA);
      __syncthreads();

      f32x4 aAe = {}, aAo = {}, aBe = {}, aBo = {};
      if (t > 0) {
#pragma unroll
        for (int kk = 0; kk < 16; kk += 2) {
          int g0 = kk * 4 + l4, g1 = (kk + 1) * 4 + l4;
          int e0 = g0 * 128 + ((l15 ^ (g0 & 15)) * 8);
          int e1 = g1 * 128 + ((l15 ^ (g1 & 15)) * 8);
          aAe = __builtin_amdgcn_mfma_f32_16x16x32_bf16(*(const short8*)&hbufA[e0], wA[kk], aAe, 0, 0, 0);
          aAo = __builtin_amdgcn_mfma_f32_16x16x32_bf16(*(const short8*)&hbufA[e1], wA[kk + 1], aAo, 0, 0, 0);
          aBe = __builtin_amdgcn_mfma_f32_16x16x32_bf16(*(const short8*)&bufX[e0], wB[kk], aBe, 0, 0, 0);
          aBo = __builtin_amdgcn_mfma_f32_16x16x32_bf16(*(const short8*)&bufX[e1], wB[kk + 1], aBo, 0, 0, 0);
        }
      } else {
#pragma unroll
        for (int kk = 0; kk < 16; kk += 2) {
          int g0 = kk * 4 + l4, g1 = (kk + 1) * 4 + l4;
          int e0 = g0 * 128 + ((l15 ^ (g0 & 15)) * 8);
          int e1 = g1 * 128 + ((l15 ^ (g1 & 15)) * 8);
          aAe = __builtin_amdgcn_mfma_f32_16x16x32_bf16(*(const short8*)&hbufA[e0], wA[kk], aAe, 0, 0, 0);
          aAo = __builtin_amdgcn_mfma_f32_16x16x32_bf16(*(const short8*)&hbufA[e1], wA[kk + 1], aAo, 0, 0, 0);
        }
      }
      f32x4 acc = (aAe + aAo) + (aBe + aBo);
#pragma unroll
      for (int r = 0; r < 4; ++r) gbuf[(wv * 64 + lane) * 5 + r] = acc[r];
      __syncthreads();
      {
        float g4[4];
#pragma unroll
        for (int s = 0; s < 4; ++s) g4[s] = gbuf[(s * 64 + lp) * 5 + ur] + b1s[s];
        float iv = sigmoidf_(g4[0]), fv = sigmoidf_(g4[1]);
        float gv = tanhf_(g4[2]), ov = sigmoidf_(g4[3]);
        cst = fv * cst + iv * gv;
        hstage[ubat * 20 + ucol] = (unsigned short)(f2bf(ov * tanhf_(cst)) + 1);
      }
      __syncthreads();
      if (tid < 64) {
        int bl = tid >> 2, q = tid & 3;
        unsigned long long v = *(const unsigned long long*)&hstage[bl * 20 + q * 4];
        cohstore_u64((unsigned long long*)(h1 + ((size_t)t * B_ + bb + bl) * H_ + colb) + q, v);
      }
      if (tid == 0) cohstore_i32(prog1 + wg2, t + 1);
    }
  }
}

// ---------------- final FC + sigmoid (decodes u16 = bf16+1) ----------------
__global__ void k_fc(const unsigned short* __restrict__ h1, const float* __restrict__ w,
                     const float* __restrict__ bfc, float* __restrict__ out) {
  int b = threadIdx.x;
  if (b < B_) {
    const unsigned short* hb = h1 + ((size_t)(T_ - 1) * B_ + b) * H_;
    float s = 0.f;
    for (int j = 0; j < H_; ++j)
      s += bf2f((unsigned short)(hb[j] - 1)) * w[j];
    out[b] = sigmoidf_(s + bfc[0]);
  }
}

extern "C" void kernel_launch(void* const* d_in, const int* in_sizes, int n_in,
                              void* d_out, int out_size, void* d_ws, size_t ws_size,
                              hipStream_t stream) {
  (void)in_sizes; (void)n_in; (void)out_size; (void)ws_size;
  const float* x    = (const float*)d_in[0];
  const float* wih0 = (const float*)d_in[1];
  const float* whh0 = (const float*)d_in[2];
  const float* bih0 = (const float*)d_in[3];
  const float* bhh0 = (const float*)d_in[4];
  const float* wih1 = (const float*)d_in[5];
  const float* whh1 = (const float*)d_in[6];
  const float* bih1 = (const float*)d_in[7];
  const float* bhh1 = (const float*)d_in[8];
  const float* wfc  = (const float*)d_in[9];
  const float* bfc  = (const float*)d_in[10];
  float* out = (float*)d_out;

  const size_t HB = (size_t)T_ * B_ * H_ * 2;   // 33.55MB per layer
  char* ws = (char*)d_ws;
  int* prog0 = (int*)ws;                        // 128 ints
  int* prog1 = (int*)(ws + 2048);               // 128 ints
  unsigned short* h0 = (unsigned short*)(ws + 4096);
  unsigned short* h1 = (unsigned short*)(ws + 4096 + HB);
  unsigned short* xT = (unsigned short*)(ws + 4096 + 2 * HB);

  // zero flags + h histories (stale-data marker = 0; fresh values are bf16+1, never 0)
  hipMemsetAsync(ws, 0, 4096 + 2 * HB, stream);
  k_convert_x<<<2048, 256, 0, stream>>>(x, xT);
  k_lstm6<<<256, 256, 0, stream>>>(xT, wih0, whh0, bih0, bhh0,
                                   wih1, whh1, bih1, bhh1, h0, h1, prog0, prog1);
  k_fc<<<1, 64, 0, stream>>>(h1, wfc, bfc, out);
}

// Round 7
// 3095.804 us; speedup vs baseline: 2.9271x; 1.1089x over previous
//
#include <hip/hip_runtime.h>
#include <stdint.h>
#include <stddef.h>

#define B_ 64
#define T_ 512
#define DIN 256
#define H_ 512
#define NWGF 128     // 64 layer-0 WGs + 64 layer-1 WGs

typedef __attribute__((ext_vector_type(8))) short short8;
typedef __attribute__((ext_vector_type(4))) float f32x4;

__device__ __forceinline__ unsigned short f2bf(float f) {
  union { float f; unsigned u; } v; v.f = f;
  return (unsigned short)((v.u + 0x7fffu + ((v.u >> 16) & 1u)) >> 16);
}
__device__ __forceinline__ float bf2f(unsigned short s) {
  union { unsigned u; float f; } v; v.u = ((unsigned)s) << 16; return v.f;
}
__device__ __forceinline__ float sigmoidf_(float x) { return 1.f / (1.f + __expf(-x)); }
__device__ __forceinline__ float tanhf_(float x) { return 1.f - 2.f / (__expf(2.f * x) + 1.f); }

// coherent (LLC, sc0|sc1) accesses -- no cache-maintenance side effects
__device__ __forceinline__ unsigned long long cohload_u64(const unsigned long long* p) {
  return __hip_atomic_load(p, __ATOMIC_RELAXED, __HIP_MEMORY_SCOPE_AGENT);
}
__device__ __forceinline__ void cohstore_u64(unsigned long long* p, unsigned long long v) {
  __hip_atomic_store(p, v, __ATOMIC_RELAXED, __HIP_MEMORY_SCOPE_AGENT);
}
// single-address counter poll: all 64 lanes load the same dword -> 1 transaction/wave
__device__ __forceinline__ void wait_ge(const int* p, int tgt) {
  while (__hip_atomic_load(p, __ATOMIC_RELAXED, __HIP_MEMORY_SCOPE_AGENT) < tgt)
    __builtin_amdgcn_s_sleep(1);
}
__device__ __forceinline__ void cnt_add(int* p) {
  __hip_atomic_fetch_add(p, 1, __ATOMIC_RELAXED, __HIP_MEMORY_SCOPE_AGENT);
}

// ---------------- convert: x [B,T,DIN] f32 -> xT [T,B,DIN] bf16 ----------------
__global__ void k_convert_x(const float* __restrict__ x, unsigned short* __restrict__ xT) {
  const int nq = T_ * B_ * DIN / 4;
  for (int q = blockIdx.x * blockDim.x + threadIdx.x; q < nq; q += gridDim.x * blockDim.x) {
    int e = q * 4;
    int d = e % DIN;
    int row = e / DIN;            // t*B + b
    int b = row & (B_ - 1), t = row / B_;
    float4 v = *(const float4*)(x + ((size_t)b * T_ + t) * DIN + d);
    unsigned short o[4] = { f2bf(v.x), f2bf(v.y), f2bf(v.z), f2bf(v.w) };
    *(uint2*)(xT + (size_t)row * DIN + d) = *(const uint2*)o;
  }
}

// ---------------- fused 2-layer persistent LSTM (v7) ----------------
// 128 WGs x 4 waves. WGs 0..63 = layer 0 (x-fused, no xg GEMM), 64..127 = layer 1.
// WG (cg,bh): h-cols [cg*16,+16), batches [bh*32,+32). Wave wv = gate section.
// Protocol (round-4 proven): coherent h stores -> vmcnt(0) -> barrier -> one
// atomic counter increment per WG. Consumers poll ONE counter dword (coalesced)
// with s_sleep backoff. Counter slot u&7, threshold 32*(u/8+1), monotone-safe.
__global__ __launch_bounds__(256, 1) void k_lstm7(
    const unsigned short* __restrict__ xT,   // [T,B,DIN] bf16
    const float* __restrict__ wih0, const float* __restrict__ whh0,
    const float* __restrict__ bih0, const float* __restrict__ bhh0,
    const float* __restrict__ wih1, const float* __restrict__ whh1,
    const float* __restrict__ bih1, const float* __restrict__ bhh1,
    unsigned short* __restrict__ h0, unsigned short* __restrict__ h1,  // [T,B,H]
    int* __restrict__ cnt0, int* __restrict__ cnt1) {  // [2 bh][8 slots] stride 16
  __shared__ unsigned short hbufA[16384];  // 32KB: h tile, elem g*256+((b^(g&7))*8)
  __shared__ unsigned short bufB[16384];   // 32KB: L0 = x dbuf [2][8192]; L1 = hbufB
  __shared__ float gbuf[8 * 64 * 5];       // 10KB gate exchange (stride-5)
  __shared__ unsigned short hstage[32 * 20];
  const int wgid = blockIdx.x;
  const int wg2 = wgid & 63;
  const int cg = wg2 >> 1, bh = wg2 & 1;
  const int tid = threadIdx.x;
  const int lane = tid & 63, wv = tid >> 6;
  const int l15 = lane & 15, l4 = lane >> 4;
  const int um = wv >> 1, rb = (wv & 1) * 2;
  const int colb = cg * 16, bb = bh * 32;

  if (wgid < 64) {
    // ================= LAYER 0 (x-fused) =================
    short8 wih[8], whh[16];
    {
      const float* wr = wih0 + (size_t)(wv * H_ + colb + l15) * DIN + l4 * 8;
#pragma unroll
      for (int kk = 0; kk < 8; ++kk) {
        float4 v0 = *(const float4*)(wr + kk * 32);
        float4 v1 = *(const float4*)(wr + kk * 32 + 4);
        unsigned short o[8] = { f2bf(v0.x), f2bf(v0.y), f2bf(v0.z), f2bf(v0.w),
                                f2bf(v1.x), f2bf(v1.y), f2bf(v1.z), f2bf(v1.w) };
        wih[kk] = *(const short8*)o;
      }
      const float* wr2 = whh0 + (size_t)(wv * H_ + colb + l15) * H_ + l4 * 8;
#pragma unroll
      for (int kk = 0; kk < 16; ++kk) {
        float4 v0 = *(const float4*)(wr2 + kk * 32);
        float4 v1 = *(const float4*)(wr2 + kk * 32 + 4);
        unsigned short o[8] = { f2bf(v0.x), f2bf(v0.y), f2bf(v0.z), f2bf(v0.w),
                                f2bf(v1.x), f2bf(v1.y), f2bf(v1.z), f2bf(v1.w) };
        whh[kk] = *(const short8*)o;
      }
    }
    float b0s[4];
#pragma unroll
    for (int s = 0; s < 4; ++s)
      b0s[s] = bih0[s * H_ + colb + l15] + bhh0[s * H_ + colb + l15];
    float c2[2] = {0.f, 0.f};

    // prologue: stage x(0) into bufB half 0 (32 rows x 32 granules of 8)
    {
#pragma unroll
      for (int j = 0; j < 4; ++j) {
        int ch = tid + j * 256;
        int b = ch >> 5, g = ch & 31;
        uint4 v = *(const uint4*)(xT + (size_t)(bb + b) * DIN + g * 8);
        *(uint4*)&bufB[g * 256 + ((b ^ (g & 7)) * 8)] = v;
      }
    }
    __syncthreads();

    for (int t = 0; t < T_; ++t) {
      // ---- 1. x-part MFMAs (tile staged last tick) ----
      f32x4 aE[2] = {}, aO[2] = {};
      {
        const unsigned short* xb = bufB + (t & 1) * 8192;
#pragma unroll
        for (int kk = 0; kk < 8; kk += 2) {
          int g0 = kk * 4 + l4, g1 = (kk + 1) * 4 + l4;
#pragma unroll
          for (int m = 0; m < 2; ++m) {
            short8 a0 = *(const short8*)&xb[g0 * 256 + (((m * 16 + l15) ^ (g0 & 7)) * 8)];
            short8 a1 = *(const short8*)&xb[g1 * 256 + (((m * 16 + l15) ^ (g1 & 7)) * 8)];
            aE[m] = __builtin_amdgcn_mfma_f32_16x16x32_bf16(a0, wih[kk], aE[m], 0, 0, 0);
            aO[m] = __builtin_amdgcn_mfma_f32_16x16x32_bf16(a1, wih[kk + 1], aO[m], 0, 0, 0);
          }
        }
      }
      // ---- 2. reg-prefetch x(t+1) ----
      uint4 xv[4];
      const bool hasx = (t + 1 < T_);
      if (hasx) {
        const unsigned short* xs = xT + (size_t)(t + 1) * (B_ * DIN);
#pragma unroll
        for (int j = 0; j < 4; ++j) {
          int ch = tid + j * 256;
          xv[j] = *(const uint4*)(xs + (size_t)(bb + (ch >> 5)) * DIN + (ch & 31) * 8);
        }
      }
      // ---- 3. wait h0(t-1) + stage ----
      if (t > 0) {
        wait_ge(cnt0 + (bh * 8 + ((t - 1) & 7)) * 16, 32 * (((t - 1) >> 3) + 1));
        asm volatile("" ::: "memory");
        const unsigned long long* hp =
            (const unsigned long long*)(h0 + ((size_t)(t - 1) * B_ + bb) * H_);
        unsigned long long tmp[16];
#pragma unroll
        for (int j = 0; j < 8; ++j) {
          size_t o = (size_t)(tid + j * 256) * 2;
          tmp[2 * j] = cohload_u64(hp + o);
          tmp[2 * j + 1] = cohload_u64(hp + o + 1);
        }
#pragma unroll
        for (int j = 0; j < 8; ++j) {
          int ch = tid + j * 256;
          int b = ch >> 6, g = ch & 63;
          union { unsigned long long q[2]; uint4 v; } u;
          u.q[0] = tmp[2 * j]; u.q[1] = tmp[2 * j + 1];
          *(uint4*)&hbufA[g * 256 + ((b ^ (g & 7)) * 8)] = u.v;
        }
      }
      // ---- 4. write x(t+1) to the other dbuf half ----
      if (hasx) {
        unsigned short* xd = bufB + ((t + 1) & 1) * 8192;
#pragma unroll
        for (int j = 0; j < 4; ++j) {
          int ch = tid + j * 256;
          int b = ch >> 5, g = ch & 31;
          *(uint4*)&xd[g * 256 + ((b ^ (g & 7)) * 8)] = xv[j];
        }
      }
      __syncthreads();
      // ---- 5. h-part MFMAs ----
      if (t > 0) {
#pragma unroll
        for (int kk = 0; kk < 16; kk += 2) {
          int g0 = kk * 4 + l4, g1 = (kk + 1) * 4 + l4;
#pragma unroll
          for (int m = 0; m < 2; ++m) {
            short8 a0 = *(const short8*)&hbufA[g0 * 256 + (((m * 16 + l15) ^ (g0 & 7)) * 8)];
            short8 a1 = *(const short8*)&hbufA[g1 * 256 + (((m * 16 + l15) ^ (g1 & 7)) * 8)];
            aE[m] = __builtin_amdgcn_mfma_f32_16x16x32_bf16(a0, whh[kk], aE[m], 0, 0, 0);
            aO[m] = __builtin_amdgcn_mfma_f32_16x16x32_bf16(a1, whh[kk + 1], aO[m], 0, 0, 0);
          }
        }
      }
      // ---- 6. gate exchange ----
#pragma unroll
      for (int m = 0; m < 2; ++m) {
        f32x4 acc = aE[m] + aO[m];
#pragma unroll
        for (int r = 0; r < 4; ++r)
          gbuf[((wv * 2 + m) * 64 + lane) * 5 + r] = acc[r];
      }
      __syncthreads();
      // ---- 7. cell update (m=um, rows rb..rb+1) ----
#pragma unroll
      for (int rr = 0; rr < 2; ++rr) {
        int r = rb + rr;
        float g4[4];
#pragma unroll
        for (int s = 0; s < 4; ++s)
          g4[s] = gbuf[((s * 2 + um) * 64 + lane) * 5 + r] + b0s[s];
        float iv = sigmoidf_(g4[0]), fv = sigmoidf_(g4[1]);
        float gv = tanhf_(g4[2]), ov = sigmoidf_(g4[3]);
        float cn = fv * c2[rr] + iv * gv;
        c2[rr] = cn;
        hstage[(um * 16 + l4 * 4 + r) * 20 + l15] = f2bf(ov * tanhf_(cn));
      }
      __syncthreads();
      // ---- 8. publish: store -> vmcnt(0) -> barrier -> counter ----
      if (tid < 128) {
        int bl = tid >> 2, q = tid & 3;
        unsigned long long v = *(const unsigned long long*)&hstage[bl * 20 + q * 4];
        cohstore_u64((unsigned long long*)(h0 + ((size_t)t * B_ + bb + bl) * H_ + colb) + q, v);
      }
      asm volatile("s_waitcnt vmcnt(0)" ::: "memory");
      __syncthreads();
      if (tid == 0) cnt_add(cnt0 + (bh * 8 + (t & 7)) * 16);
    }
  } else {
    // ================= LAYER 1 =================
    short8 wA[16], wB[16];
    {
      const float* wrA = wih1 + (size_t)(wv * H_ + colb + l15) * H_ + l4 * 8;
      const float* wrB = whh1 + (size_t)(wv * H_ + colb + l15) * H_ + l4 * 8;
#pragma unroll
      for (int kk = 0; kk < 16; ++kk) {
        float4 a0 = *(const float4*)(wrA + kk * 32);
        float4 a1 = *(const float4*)(wrA + kk * 32 + 4);
        unsigned short oa[8] = { f2bf(a0.x), f2bf(a0.y), f2bf(a0.z), f2bf(a0.w),
                                 f2bf(a1.x), f2bf(a1.y), f2bf(a1.z), f2bf(a1.w) };
        wA[kk] = *(const short8*)oa;
        float4 b0 = *(const float4*)(wrB + kk * 32);
        float4 b1 = *(const float4*)(wrB + kk * 32 + 4);
        unsigned short ob[8] = { f2bf(b0.x), f2bf(b0.y), f2bf(b0.z), f2bf(b0.w),
                                 f2bf(b1.x), f2bf(b1.y), f2bf(b1.z), f2bf(b1.w) };
        wB[kk] = *(const short8*)ob;
      }
    }
    float b1s[4];
#pragma unroll
    for (int s = 0; s < 4; ++s)
      b1s[s] = bih1[s * H_ + colb + l15] + bhh1[s * H_ + colb + l15];
    float c2[2] = {0.f, 0.f};

    for (int t = 0; t < T_; ++t) {
      // ---- wait h0(t) (and peers' h1(t-1)), then stage ----
      wait_ge(cnt0 + (bh * 8 + (t & 7)) * 16, 32 * ((t >> 3) + 1));
      if (t > 0)
        wait_ge(cnt1 + (bh * 8 + ((t - 1) & 7)) * 16, 32 * (((t - 1) >> 3) + 1));
      asm volatile("" ::: "memory");
      {
        const unsigned long long* hpA =
            (const unsigned long long*)(h0 + ((size_t)t * B_ + bb) * H_);
        const unsigned long long* hpB =
            (const unsigned long long*)(h1 + ((size_t)(t - 1) * B_ + bb) * H_);
        unsigned long long ta[16], tb[16];
#pragma unroll
        for (int j = 0; j < 8; ++j) {
          size_t o = (size_t)(tid + j * 256) * 2;
          ta[2 * j] = cohload_u64(hpA + o);
          ta[2 * j + 1] = cohload_u64(hpA + o + 1);
        }
        if (t > 0) {
#pragma unroll
          for (int j = 0; j < 8; ++j) {
            size_t o = (size_t)(tid + j * 256) * 2;
            tb[2 * j] = cohload_u64(hpB + o);
            tb[2 * j + 1] = cohload_u64(hpB + o + 1);
          }
        }
#pragma unroll
        for (int j = 0; j < 8; ++j) {
          int ch = tid + j * 256;
          int b = ch >> 6, g = ch & 63;
          int el = g * 256 + ((b ^ (g & 7)) * 8);
          union { unsigned long long q[2]; uint4 v; } u;
          u.q[0] = ta[2 * j]; u.q[1] = ta[2 * j + 1];
          *(uint4*)&hbufA[el] = u.v;
          if (t > 0) {
            u.q[0] = tb[2 * j]; u.q[1] = tb[2 * j + 1];
            *(uint4*)&bufB[el] = u.v;
          }
        }
      }
      __syncthreads();

      f32x4 aA[2] = {}, aB[2] = {};
#pragma unroll
      for (int kk = 0; kk < 16; ++kk) {
        int g = kk * 4 + l4;
#pragma unroll
        for (int m = 0; m < 2; ++m) {
          int e = g * 256 + (((m * 16 + l15) ^ (g & 7)) * 8);
          aA[m] = __builtin_amdgcn_mfma_f32_16x16x32_bf16(*(const short8*)&hbufA[e], wA[kk], aA[m], 0, 0, 0);
          if (t > 0)
            aB[m] = __builtin_amdgcn_mfma_f32_16x16x32_bf16(*(const short8*)&bufB[e], wB[kk], aB[m], 0, 0, 0);
        }
      }

#pragma unroll
      for (int m = 0; m < 2; ++m) {
        f32x4 acc = aA[m] + aB[m];
#pragma unroll
        for (int r = 0; r < 4; ++r)
          gbuf[((wv * 2 + m) * 64 + lane) * 5 + r] = acc[r];
      }
      __syncthreads();

#pragma unroll
      for (int rr = 0; rr < 2; ++rr) {
        int r = rb + rr;
        float g4[4];
#pragma unroll
        for (int s = 0; s < 4; ++s)
          g4[s] = gbuf[((s * 2 + um) * 64 + lane) * 5 + r] + b1s[s];
        float iv = sigmoidf_(g4[0]), fv = sigmoidf_(g4[1]);
        float gv = tanhf_(g4[2]), ov = sigmoidf_(g4[3]);
        float cn = fv * c2[rr] + iv * gv;
        c2[rr] = cn;
        hstage[(um * 16 + l4 * 4 + r) * 20 + l15] = f2bf(ov * tanhf_(cn));
      }
      __syncthreads();

      if (tid < 128) {
        int bl = tid >> 2, q = tid & 3;
        unsigned long long v = *(const unsigned long long*)&hstage[bl * 20 + q * 4];
        cohstore_u64((unsigned long long*)(h1 + ((size_t)t * B_ + bb + bl) * H_ + colb) + q, v);
      }
      asm volatile("s_waitcnt vmcnt(0)" ::: "memory");
      __syncthreads();
      if (tid == 0) cnt_add(cnt1 + (bh * 8 + (t & 7)) * 16);
    }
  }
}

// ---------------- final FC + sigmoid ----------------
__global__ void k_fc(const unsigned short* __restrict__ h1, const float* __restrict__ w,
                     const float* __restrict__ bfc, float* __restrict__ out) {
  int b = threadIdx.x;
  if (b < B_) {
    const unsigned short* hb = h1 + ((size_t)(T_ - 1) * B_ + b) * H_;
    float s = 0.f;
    for (int j = 0; j < H_; ++j) s += bf2f(hb[j]) * w[j];
    out[b] = sigmoidf_(s + bfc[0]);
  }
}

extern "C" void kernel_launch(void* const* d_in, const int* in_sizes, int n_in,
                              void* d_out, int out_size, void* d_ws, size_t ws_size,
                              hipStream_t stream) {
  (void)in_sizes; (void)n_in; (void)out_size; (void)ws_size;
  const float* x    = (const float*)d_in[0];
  const float* wih0 = (const float*)d_in[1];
  const float* whh0 = (const float*)d_in[2];
  const float* bih0 = (const float*)d_in[3];
  const float* bhh0 = (const float*)d_in[4];
  const float* wih1 = (const float*)d_in[5];
  const float* whh1 = (const float*)d_in[6];
  const float* bih1 = (const float*)d_in[7];
  const float* bhh1 = (const float*)d_in[8];
  const float* wfc  = (const float*)d_in[9];
  const float* bfc  = (const float*)d_in[10];
  float* out = (float*)d_out;

  const size_t HB = (size_t)T_ * B_ * H_ * 2;   // 33.55MB per layer
  char* ws = (char*)d_ws;
  int* cnt0 = (int*)ws;                         // [2][8] stride-16 ints
  int* cnt1 = (int*)(ws + 2048);
  unsigned short* h0 = (unsigned short*)(ws + 4096);
  unsigned short* h1 = (unsigned short*)(ws + 4096 + HB);
  unsigned short* xT = (unsigned short*)(ws + 4096 + 2 * HB);

  hipMemsetAsync(ws, 0, 4096, stream);   // counters must start at 0 each replay
  k_convert_x<<<2048, 256, 0, stream>>>(x, xT);
  k_lstm7<<<NWGF, 256, 0, stream>>>(xT, wih0, whh0, bih0, bhh0,
                                    wih1, whh1, bih1, bhh1, h0, h1, cnt0, cnt1);
  k_fc<<<1, 64, 0, stream>>>(h1, wfc, bfc, out);
}

// Round 8
// 1845.111 us; speedup vs baseline: 4.9112x; 1.6778x over previous
//
#include <hip/hip_runtime.h>
#include <stdint.h>
#include <stddef.h>

#define B_ 64
#define T_ 512
#define DIN 256
#define H_ 512
#define NWGF 128     // 64 layer-0 WGs + 64 layer-1 WGs

typedef __attribute__((ext_vector_type(8))) short short8;
typedef __attribute__((ext_vector_type(4))) float f32x4;

__device__ __forceinline__ unsigned short f2bf(float f) {
  union { float f; unsigned u; } v; v.f = f;
  return (unsigned short)((v.u + 0x7fffu + ((v.u >> 16) & 1u)) >> 16);
}
__device__ __forceinline__ float bf2f(unsigned short s) {
  union { unsigned u; float f; } v; v.u = ((unsigned)s) << 16; return v.f;
}
__device__ __forceinline__ float sigmoidf_(float x) { return 1.f / (1.f + __expf(-x)); }
__device__ __forceinline__ float tanhf_(float x) { return 1.f - 2.f / (__expf(2.f * x) + 1.f); }

// coherent (LLC, sc0|sc1) accesses for h STORES + flags only
__device__ __forceinline__ void cohstore_u64(unsigned long long* p, unsigned long long v) {
  __hip_atomic_store(p, v, __ATOMIC_RELAXED, __HIP_MEMORY_SCOPE_AGENT);
}
__device__ __forceinline__ int cohload_i32(const int* p) {
  return __hip_atomic_load(p, __ATOMIC_RELAXED, __HIP_MEMORY_SCOPE_AGENT);
}
__device__ __forceinline__ void cohstore_i32(int* p, int v) {
  __hip_atomic_store(p, v, __ATOMIC_RELAXED, __HIP_MEMORY_SCOPE_AGENT);
}

// ---------------- convert: x [B,T,DIN] f32 -> xT [T,B,DIN] bf16 ----------------
__global__ void k_convert_x(const float* __restrict__ x, unsigned short* __restrict__ xT) {
  const int nq = T_ * B_ * DIN / 4;
  for (int q = blockIdx.x * blockDim.x + threadIdx.x; q < nq; q += gridDim.x * blockDim.x) {
    int e = q * 4;
    int d = e % DIN;
    int row = e / DIN;            // t*B + b
    int b = row & (B_ - 1), t = row / B_;
    float4 v = *(const float4*)(x + ((size_t)b * T_ + t) * DIN + d);
    unsigned short o[4] = { f2bf(v.x), f2bf(v.y), f2bf(v.z), f2bf(v.w) };
    *(uint2*)(xT + (size_t)row * DIN + d) = *(const uint2*)o;
  }
}

// ---------------- fused 2-layer persistent LSTM (v8) ----------------
// 128 WGs x 4 waves. WGs 0..63 = layer 0 (x-fused), 64..127 = layer 1.
// WG (cg,bh): h-cols [cg*16,+16), batches [bh*32,+32). Wave wv = gate section.
// Protocol: h stores sc0|sc1 (write-through to MALL) -> vmcnt(0) -> barrier ->
// per-WG flag line (plain relaxed store, own 128B line). Consumers poll 32 flag
// lines (1 vector load) then stage h via PLAIN CACHED loads (each h address is
// written once and first touched post-flag -> L2 race-free; L2 broadcast serves
// XCD-mates at hit latency). L1 overlaps its h1 B-matmul with the h0 wait.
__global__ __launch_bounds__(256, 1) void k_lstm8(
    const unsigned short* __restrict__ xT,   // [T,B,DIN] bf16
    const float* __restrict__ wih0, const float* __restrict__ whh0,
    const float* __restrict__ bih0, const float* __restrict__ bhh0,
    const float* __restrict__ wih1, const float* __restrict__ whh1,
    const float* __restrict__ bih1, const float* __restrict__ bhh1,
    unsigned short* __restrict__ h0, unsigned short* __restrict__ h1,  // [T,B,H]
    int* __restrict__ flags0, int* __restrict__ flags1) {  // 64 x stride-32 ints
  __shared__ unsigned short hbufA[16384];  // 32KB: elem g*256+((b^(g&7))*8)
  __shared__ unsigned short bufB[16384];   // 32KB: L0 = x dbuf [2][8192]; L1 = h1 tile
  __shared__ float gbuf[8 * 64 * 5];       // 10KB gate exchange (stride-5)
  __shared__ unsigned short hstage[32 * 20];
  const int wgid = blockIdx.x;
  const int wg2 = wgid & 63;
  const int cg = wg2 >> 1, bh = wg2 & 1;
  const int tid = threadIdx.x;
  const int lane = tid & 63, wv = tid >> 6;
  const int l15 = lane & 15, l4 = lane >> 4;
  const int um = wv >> 1, rb = (wv & 1) * 2;
  const int colb = cg * 16, bb = bh * 32;

  if (wgid < 64) {
    // ================= LAYER 0 (x-fused) =================
    short8 wih[8], whh[16];
    {
      const float* wr = wih0 + (size_t)(wv * H_ + colb + l15) * DIN + l4 * 8;
#pragma unroll
      for (int kk = 0; kk < 8; ++kk) {
        float4 v0 = *(const float4*)(wr + kk * 32);
        float4 v1 = *(const float4*)(wr + kk * 32 + 4);
        unsigned short o[8] = { f2bf(v0.x), f2bf(v0.y), f2bf(v0.z), f2bf(v0.w),
                                f2bf(v1.x), f2bf(v1.y), f2bf(v1.z), f2bf(v1.w) };
        wih[kk] = *(const short8*)o;
      }
      const float* wr2 = whh0 + (size_t)(wv * H_ + colb + l15) * H_ + l4 * 8;
#pragma unroll
      for (int kk = 0; kk < 16; ++kk) {
        float4 v0 = *(const float4*)(wr2 + kk * 32);
        float4 v1 = *(const float4*)(wr2 + kk * 32 + 4);
        unsigned short o[8] = { f2bf(v0.x), f2bf(v0.y), f2bf(v0.z), f2bf(v0.w),
                                f2bf(v1.x), f2bf(v1.y), f2bf(v1.z), f2bf(v1.w) };
        whh[kk] = *(const short8*)o;
      }
    }
    float b0s[4];
#pragma unroll
    for (int s = 0; s < 4; ++s)
      b0s[s] = bih0[s * H_ + colb + l15] + bhh0[s * H_ + colb + l15];
    float c2[2] = {0.f, 0.f};

    // prologue: stage x(0)
    {
#pragma unroll
      for (int j = 0; j < 4; ++j) {
        int ch = tid + j * 256;
        int b = ch >> 5, g = ch & 31;
        uint4 v = *(const uint4*)(xT + (size_t)(bb + b) * DIN + g * 8);
        *(uint4*)&bufB[g * 256 + ((b ^ (g & 7)) * 8)] = v;
      }
    }
    __syncthreads();

    for (int t = 0; t < T_; ++t) {
      // ---- 1. x-part MFMAs ----
      f32x4 aE[2] = {}, aO[2] = {};
      {
        const unsigned short* xb = bufB + (t & 1) * 8192;
#pragma unroll
        for (int kk = 0; kk < 8; kk += 2) {
          int g0 = kk * 4 + l4, g1 = (kk + 1) * 4 + l4;
#pragma unroll
          for (int m = 0; m < 2; ++m) {
            short8 a0 = *(const short8*)&xb[g0 * 256 + (((m * 16 + l15) ^ (g0 & 7)) * 8)];
            short8 a1 = *(const short8*)&xb[g1 * 256 + (((m * 16 + l15) ^ (g1 & 7)) * 8)];
            aE[m] = __builtin_amdgcn_mfma_f32_16x16x32_bf16(a0, wih[kk], aE[m], 0, 0, 0);
            aO[m] = __builtin_amdgcn_mfma_f32_16x16x32_bf16(a1, wih[kk + 1], aO[m], 0, 0, 0);
          }
        }
      }
      // ---- 2. reg-prefetch x(t+1) (in flight during the wait) ----
      uint4 xv[4];
      const bool hasx = (t + 1 < T_);
      if (hasx) {
        const unsigned short* xs = xT + (size_t)(t + 1) * (B_ * DIN);
#pragma unroll
        for (int j = 0; j < 4; ++j) {
          int ch = tid + j * 256;
          xv[j] = *(const uint4*)(xs + (size_t)(bb + (ch >> 5)) * DIN + (ch & 31) * 8);
        }
      }
      // ---- 3. wait h0(t-1) flags, stage via cached loads ----
      if (t > 0) {
        for (;;) {
          int v = (lane < 32) ? cohload_i32(flags0 + (lane * 2 + bh) * 32) : 0x7fffffff;
          if (__all(v >= t)) break;
          __builtin_amdgcn_s_sleep(1);
        }
        __builtin_amdgcn_sched_barrier(0);
        asm volatile("" ::: "memory");
        const uint4* hp = (const uint4*)(h0 + ((size_t)(t - 1) * B_ + bb) * H_);
        uint4 tmp[8];
#pragma unroll
        for (int j = 0; j < 8; ++j) tmp[j] = hp[tid + j * 256];
#pragma unroll
        for (int j = 0; j < 8; ++j) {
          int ch = tid + j * 256;
          int b = ch >> 6, g = ch & 63;
          *(uint4*)&hbufA[g * 256 + ((b ^ (g & 7)) * 8)] = tmp[j];
        }
      }
      // ---- 4. x(t+1) -> other dbuf half ----
      if (hasx) {
        unsigned short* xd = bufB + ((t + 1) & 1) * 8192;
#pragma unroll
        for (int j = 0; j < 4; ++j) {
          int ch = tid + j * 256;
          int b = ch >> 5, g = ch & 31;
          *(uint4*)&xd[g * 256 + ((b ^ (g & 7)) * 8)] = xv[j];
        }
      }
      __syncthreads();
      // ---- 5. h-part MFMAs ----
      if (t > 0) {
#pragma unroll
        for (int kk = 0; kk < 16; kk += 2) {
          int g0 = kk * 4 + l4, g1 = (kk + 1) * 4 + l4;
#pragma unroll
          for (int m = 0; m < 2; ++m) {
            short8 a0 = *(const short8*)&hbufA[g0 * 256 + (((m * 16 + l15) ^ (g0 & 7)) * 8)];
            short8 a1 = *(const short8*)&hbufA[g1 * 256 + (((m * 16 + l15) ^ (g1 & 7)) * 8)];
            aE[m] = __builtin_amdgcn_mfma_f32_16x16x32_bf16(a0, whh[kk], aE[m], 0, 0, 0);
            aO[m] = __builtin_amdgcn_mfma_f32_16x16x32_bf16(a1, whh[kk + 1], aO[m], 0, 0, 0);
          }
        }
      }
      // ---- 6. gate exchange ----
#pragma unroll
      for (int m = 0; m < 2; ++m) {
        f32x4 acc = aE[m] + aO[m];
#pragma unroll
        for (int r = 0; r < 4; ++r)
          gbuf[((wv * 2 + m) * 64 + lane) * 5 + r] = acc[r];
      }
      __syncthreads();
      // ---- 7. cell update ----
#pragma unroll
      for (int rr = 0; rr < 2; ++rr) {
        int r = rb + rr;
        float g4[4];
#pragma unroll
        for (int s = 0; s < 4; ++s)
          g4[s] = gbuf[((s * 2 + um) * 64 + lane) * 5 + r] + b0s[s];
        float iv = sigmoidf_(g4[0]), fv = sigmoidf_(g4[1]);
        float gv = tanhf_(g4[2]), ov = sigmoidf_(g4[3]);
        float cn = fv * c2[rr] + iv * gv;
        c2[rr] = cn;
        hstage[(um * 16 + l4 * 4 + r) * 20 + l15] = f2bf(ov * tanhf_(cn));
      }
      __syncthreads();
      // ---- 8. publish ----
      if (tid < 128) {
        int bl = tid >> 2, q = tid & 3;
        unsigned long long v = *(const unsigned long long*)&hstage[bl * 20 + q * 4];
        cohstore_u64((unsigned long long*)(h0 + ((size_t)t * B_ + bb + bl) * H_ + colb) + q, v);
      }
      asm volatile("s_waitcnt vmcnt(0)" ::: "memory");
      __syncthreads();
      if (tid == 0) cohstore_i32(flags0 + wg2 * 32, t + 1);
    }
  } else {
    // ================= LAYER 1 =================
    short8 wA[16], wB[16];
    {
      const float* wrA = wih1 + (size_t)(wv * H_ + colb + l15) * H_ + l4 * 8;
      const float* wrB = whh1 + (size_t)(wv * H_ + colb + l15) * H_ + l4 * 8;
#pragma unroll
      for (int kk = 0; kk < 16; ++kk) {
        float4 a0 = *(const float4*)(wrA + kk * 32);
        float4 a1 = *(const float4*)(wrA + kk * 32 + 4);
        unsigned short oa[8] = { f2bf(a0.x), f2bf(a0.y), f2bf(a0.z), f2bf(a0.w),
                                 f2bf(a1.x), f2bf(a1.y), f2bf(a1.z), f2bf(a1.w) };
        wA[kk] = *(const short8*)oa;
        float4 b0 = *(const float4*)(wrB + kk * 32);
        float4 b1 = *(const float4*)(wrB + kk * 32 + 4);
        unsigned short ob[8] = { f2bf(b0.x), f2bf(b0.y), f2bf(b0.z), f2bf(b0.w),
                                 f2bf(b1.x), f2bf(b1.y), f2bf(b1.z), f2bf(b1.w) };
        wB[kk] = *(const short8*)ob;
      }
    }
    float b1s[4];
#pragma unroll
    for (int s = 0; s < 4; ++s)
      b1s[s] = bih1[s * H_ + colb + l15] + bhh1[s * H_ + colb + l15];
    float c2[2] = {0.f, 0.f};

    for (int t = 0; t < T_; ++t) {
      f32x4 aA[2] = {}, aB[2] = {};
      // ---- phase B: own-layer h1(t-1) staged + matmul BEFORE waiting on h0(t) ----
      if (t > 0) {
        for (;;) {
          int v = (lane < 32) ? cohload_i32(flags1 + (lane * 2 + bh) * 32) : 0x7fffffff;
          if (__all(v >= t)) break;
          __builtin_amdgcn_s_sleep(1);
        }
        __builtin_amdgcn_sched_barrier(0);
        asm volatile("" ::: "memory");
        const uint4* hp = (const uint4*)(h1 + ((size_t)(t - 1) * B_ + bb) * H_);
        uint4 tmp[8];
#pragma unroll
        for (int j = 0; j < 8; ++j) tmp[j] = hp[tid + j * 256];
#pragma unroll
        for (int j = 0; j < 8; ++j) {
          int ch = tid + j * 256;
          int b = ch >> 6, g = ch & 63;
          *(uint4*)&bufB[g * 256 + ((b ^ (g & 7)) * 8)] = tmp[j];
        }
        __syncthreads();
#pragma unroll
        for (int kk = 0; kk < 16; ++kk) {
          int g = kk * 4 + l4;
#pragma unroll
          for (int m = 0; m < 2; ++m) {
            int e = g * 256 + (((m * 16 + l15) ^ (g & 7)) * 8);
            aB[m] = __builtin_amdgcn_mfma_f32_16x16x32_bf16(*(const short8*)&bufB[e], wB[kk], aB[m], 0, 0, 0);
          }
        }
      }
      // ---- phase A: wait h0(t), stage, matmul ----
      for (;;) {
        int v = (lane < 32) ? cohload_i32(flags0 + (lane * 2 + bh) * 32) : 0x7fffffff;
        if (__all(v >= t + 1)) break;
        __builtin_amdgcn_s_sleep(1);
      }
      __builtin_amdgcn_sched_barrier(0);
      asm volatile("" ::: "memory");
      {
        const uint4* hp = (const uint4*)(h0 + ((size_t)t * B_ + bb) * H_);
        uint4 tmp[8];
#pragma unroll
        for (int j = 0; j < 8; ++j) tmp[j] = hp[tid + j * 256];
#pragma unroll
        for (int j = 0; j < 8; ++j) {
          int ch = tid + j * 256;
          int b = ch >> 6, g = ch & 63;
          *(uint4*)&hbufA[g * 256 + ((b ^ (g & 7)) * 8)] = tmp[j];
        }
      }
      __syncthreads();
#pragma unroll
      for (int kk = 0; kk < 16; ++kk) {
        int g = kk * 4 + l4;
#pragma unroll
        for (int m = 0; m < 2; ++m) {
          int e = g * 256 + (((m * 16 + l15) ^ (g & 7)) * 8);
          aA[m] = __builtin_amdgcn_mfma_f32_16x16x32_bf16(*(const short8*)&hbufA[e], wA[kk], aA[m], 0, 0, 0);
        }
      }
      // ---- exchange + update + publish ----
#pragma unroll
      for (int m = 0; m < 2; ++m) {
        f32x4 acc = aA[m] + aB[m];
#pragma unroll
        for (int r = 0; r < 4; ++r)
          gbuf[((wv * 2 + m) * 64 + lane) * 5 + r] = acc[r];
      }
      __syncthreads();
#pragma unroll
      for (int rr = 0; rr < 2; ++rr) {
        int r = rb + rr;
        float g4[4];
#pragma unroll
        for (int s = 0; s < 4; ++s)
          g4[s] = gbuf[((s * 2 + um) * 64 + lane) * 5 + r] + b1s[s];
        float iv = sigmoidf_(g4[0]), fv = sigmoidf_(g4[1]);
        float gv = tanhf_(g4[2]), ov = sigmoidf_(g4[3]);
        float cn = fv * c2[rr] + iv * gv;
        c2[rr] = cn;
        hstage[(um * 16 + l4 * 4 + r) * 20 + l15] = f2bf(ov * tanhf_(cn));
      }
      __syncthreads();
      if (tid < 128) {
        int bl = tid >> 2, q = tid & 3;
        unsigned long long v = *(const unsigned long long*)&hstage[bl * 20 + q * 4];
        cohstore_u64((unsigned long long*)(h1 + ((size_t)t * B_ + bb + bl) * H_ + colb) + q, v);
      }
      asm volatile("s_waitcnt vmcnt(0)" ::: "memory");
      __syncthreads();
      if (tid == 0) cohstore_i32(flags1 + wg2 * 32, t + 1);
    }
  }
}

// ---------------- final FC + sigmoid ----------------
__global__ void k_fc(const unsigned short* __restrict__ h1, const float* __restrict__ w,
                     const float* __restrict__ bfc, float* __restrict__ out) {
  int b = threadIdx.x;
  if (b < B_) {
    const unsigned short* hb = h1 + ((size_t)(T_ - 1) * B_ + b) * H_;
    float s = 0.f;
    for (int j = 0; j < H_; ++j) s += bf2f(hb[j]) * w[j];
    out[b] = sigmoidf_(s + bfc[0]);
  }
}

extern "C" void kernel_launch(void* const* d_in, const int* in_sizes, int n_in,
                              void* d_out, int out_size, void* d_ws, size_t ws_size,
                              hipStream_t stream) {
  (void)in_sizes; (void)n_in; (void)out_size; (void)ws_size;
  const float* x    = (const float*)d_in[0];
  const float* wih0 = (const float*)d_in[1];
  const float* whh0 = (const float*)d_in[2];
  const float* bih0 = (const float*)d_in[3];
  const float* bhh0 = (const float*)d_in[4];
  const float* wih1 = (const float*)d_in[5];
  const float* whh1 = (const float*)d_in[6];
  const float* bih1 = (const float*)d_in[7];
  const float* bhh1 = (const float*)d_in[8];
  const float* wfc  = (const float*)d_in[9];
  const float* bfc  = (const float*)d_in[10];
  float* out = (float*)d_out;

  const size_t HB = (size_t)T_ * B_ * H_ * 2;   // 33.55MB per layer
  char* ws = (char*)d_ws;
  int* flags0 = (int*)ws;                       // 64 x stride-32 ints = 8KB
  int* flags1 = (int*)(ws + 8192);              // 8KB
  unsigned short* h0 = (unsigned short*)(ws + 16384);
  unsigned short* h1 = (unsigned short*)(ws + 16384 + HB);
  unsigned short* xT = (unsigned short*)(ws + 16384 + 2 * HB);

  hipMemsetAsync(ws, 0, 16384, stream);   // flags must start at 0 each replay
  k_convert_x<<<2048, 256, 0, stream>>>(x, xT);
  k_lstm8<<<NWGF, 256, 0, stream>>>(xT, wih0, whh0, bih0, bhh0,
                                    wih1, whh1, bih1, bhh1, h0, h1, flags0, flags1);
  k_fc<<<1, 64, 0, stream>>>(h1, wfc, bfc, out);
}

// Round 9
// 1841.890 us; speedup vs baseline: 4.9197x; 1.0017x over previous
//
#include <hip/hip_runtime.h>
#include <stdint.h>
#include <stddef.h>

#define B_ 64
#define T_ 512
#define DIN 256
#define H_ 512
#define NWGF 256     // 8 groups (layer x batch-quarter) x 32 col-group WGs

typedef __attribute__((ext_vector_type(8))) short short8;
typedef __attribute__((ext_vector_type(4))) float f32x4;

__device__ __forceinline__ unsigned short f2bf(float f) {
  union { float f; unsigned u; } v; v.f = f;
  return (unsigned short)((v.u + 0x7fffu + ((v.u >> 16) & 1u)) >> 16);
}
__device__ __forceinline__ float bf2f(unsigned short s) {
  union { unsigned u; float f; } v; v.u = ((unsigned)s) << 16; return v.f;
}
__device__ __forceinline__ float sigmoidf_(float x) { return 1.f / (1.f + __expf(-x)); }
__device__ __forceinline__ float tanhf_(float x) { return 1.f - 2.f / (__expf(2.f * x) + 1.f); }

// coherent (LLC, sc0|sc1) accesses for h stores + flags; no cache maintenance
__device__ __forceinline__ void cohstore_u64(unsigned long long* p, unsigned long long v) {
  __hip_atomic_store(p, v, __ATOMIC_RELAXED, __HIP_MEMORY_SCOPE_AGENT);
}
__device__ __forceinline__ int cohload_i32(const int* p) {
  return __hip_atomic_load(p, __ATOMIC_RELAXED, __HIP_MEMORY_SCOPE_AGENT);
}
__device__ __forceinline__ void cohstore_i32(int* p, int v) {
  __hip_atomic_store(p, v, __ATOMIC_RELAXED, __HIP_MEMORY_SCOPE_AGENT);
}

// ---------------- convert: x [B,T,DIN] f32 -> xT [T,B,DIN] bf16 ----------------
__global__ void k_convert_x(const float* __restrict__ x, unsigned short* __restrict__ xT) {
  const int nq = T_ * B_ * DIN / 4;
  for (int q = blockIdx.x * blockDim.x + threadIdx.x; q < nq; q += gridDim.x * blockDim.x) {
    int e = q * 4;
    int d = e % DIN;
    int row = e / DIN;            // t*B + b
    int b = row & (B_ - 1), t = row / B_;
    float4 v = *(const float4*)(x + ((size_t)b * T_ + t) * DIN + d);
    unsigned short o[4] = { f2bf(v.x), f2bf(v.y), f2bf(v.z), f2bf(v.w) };
    *(uint2*)(xT + (size_t)row * DIN + d) = *(const uint2*)o;
  }
}

// ---------------- fused 2-layer persistent LSTM (v9: XCD-local groups) ----------------
// 256 WGs x 4 waves, 1 WG/CU. group = bid & 7 (intended XCD via round-robin);
// cg = bid >> 3 (col-group, 16 h-cols). group = layer*4 + batch-quarter (16 batches).
// All intra-layer communication (flags + h tiles) stays within a group -> same XCD
// L2; only the L0->L1 h0 handoff crosses XCDs (hidden under L1's own-layer B-phase
// by register prefetch). Protocol identical to v8 (proven): sc0sc1 h stores ->
// vmcnt(0) -> barrier -> per-WG flag line; consumers poll then plain cached loads.
__global__ __launch_bounds__(256, 1) void k_lstm9(
    const unsigned short* __restrict__ xT,   // [T,B,DIN] bf16
    const float* __restrict__ wih0, const float* __restrict__ whh0,
    const float* __restrict__ bih0, const float* __restrict__ bhh0,
    const float* __restrict__ wih1, const float* __restrict__ whh1,
    const float* __restrict__ bih1, const float* __restrict__ bhh1,
    unsigned short* __restrict__ h0, unsigned short* __restrict__ h1,  // [T,B,H]
    int* __restrict__ flg) {                 // 256 WGs x 128B flag lines
  __shared__ unsigned short hbufA[8192];   // 16KB h tile: elem g*128+((b^(g&15))*8)
  __shared__ unsigned short bufB[8192];    // 16KB: L0 = x dbuf [2][4096]; L1 = h1 tile
  __shared__ float gbuf[4 * 64 * 5];       // 5KB gate exchange (stride-5)
  __shared__ unsigned short hstage[16 * 20];
  const int bid = blockIdx.x;
  const int grp = bid & 7, cg = bid >> 3;
  const int layer = grp >> 2, bq = grp & 3;
  const int tid = threadIdx.x;
  const int lane = tid & 63, wv = tid >> 6;
  const int l15 = lane & 15, l4 = lane >> 4;
  const int colb = cg * 16, bb = bq * 16;
  const int ucol = tid & 15, ubat = tid >> 4;            // update cell (row=ubat,col=ucol)
  const int lp = (ubat >> 2) * 16 + ucol, ur = ubat & 3; // gbuf source for that cell
  int* myflag = flg + (grp * 32 + cg) * 32;
  const int* f_own = flg + (grp * 32) * 32;              // own group's flag block
  const int* f_l0  = flg + (bq * 32) * 32;               // layer-0 group (for L1)

  if (layer == 0) {
    // ================= LAYER 0 (x-fused) =================
    short8 wih[8], whh[16];
    {
      const float* wr = wih0 + (size_t)(wv * H_ + colb + l15) * DIN + l4 * 8;
#pragma unroll
      for (int kk = 0; kk < 8; ++kk) {
        float4 v0 = *(const float4*)(wr + kk * 32);
        float4 v1 = *(const float4*)(wr + kk * 32 + 4);
        unsigned short o[8] = { f2bf(v0.x), f2bf(v0.y), f2bf(v0.z), f2bf(v0.w),
                                f2bf(v1.x), f2bf(v1.y), f2bf(v1.z), f2bf(v1.w) };
        wih[kk] = *(const short8*)o;
      }
      const float* wr2 = whh0 + (size_t)(wv * H_ + colb + l15) * H_ + l4 * 8;
#pragma unroll
      for (int kk = 0; kk < 16; ++kk) {
        float4 v0 = *(const float4*)(wr2 + kk * 32);
        float4 v1 = *(const float4*)(wr2 + kk * 32 + 4);
        unsigned short o[8] = { f2bf(v0.x), f2bf(v0.y), f2bf(v0.z), f2bf(v0.w),
                                f2bf(v1.x), f2bf(v1.y), f2bf(v1.z), f2bf(v1.w) };
        whh[kk] = *(const short8*)o;
      }
    }
    float b0s[4];
#pragma unroll
    for (int s = 0; s < 4; ++s)
      b0s[s] = bih0[s * H_ + colb + ucol] + bhh0[s * H_ + colb + ucol];
    float cst = 0.f;

    // prologue: stage x(0) into dbuf half 0 (16 rows x 32 granules)
#pragma unroll
    for (int j = 0; j < 2; ++j) {
      int ch = tid + j * 256;
      int b = ch >> 5, g = ch & 31;
      uint4 v = *(const uint4*)(xT + (size_t)(bb + b) * DIN + g * 8);
      *(uint4*)&bufB[g * 128 + ((b ^ (g & 15)) * 8)] = v;
    }
    __syncthreads();

    for (int t = 0; t < T_; ++t) {
      // ---- 1. x-part MFMAs ----
      f32x4 aE = {}, aO = {};
      {
        const unsigned short* xb = bufB + (t & 1) * 4096;
#pragma unroll
        for (int kk = 0; kk < 8; kk += 2) {
          int g0 = kk * 4 + l4, g1 = (kk + 1) * 4 + l4;
          short8 a0 = *(const short8*)&xb[g0 * 128 + ((l15 ^ (g0 & 15)) * 8)];
          short8 a1 = *(const short8*)&xb[g1 * 128 + ((l15 ^ (g1 & 15)) * 8)];
          aE = __builtin_amdgcn_mfma_f32_16x16x32_bf16(a0, wih[kk], aE, 0, 0, 0);
          aO = __builtin_amdgcn_mfma_f32_16x16x32_bf16(a1, wih[kk + 1], aO, 0, 0, 0);
        }
      }
      // ---- 2. reg-prefetch x(t+1) ----
      uint4 xv[2];
      const bool hasx = (t + 1 < T_);
      if (hasx) {
        const unsigned short* xs = xT + (size_t)(t + 1) * (B_ * DIN);
#pragma unroll
        for (int j = 0; j < 2; ++j) {
          int ch = tid + j * 256;
          xv[j] = *(const uint4*)(xs + (size_t)(bb + (ch >> 5)) * DIN + (ch & 31) * 8);
        }
      }
      // ---- 3. wait h0(t-1) (group-local flags), stage via cached loads ----
      if (t > 0) {
        for (;;) {
          int v = (lane < 32) ? cohload_i32(f_own + lane * 32) : 0x7fffffff;
          if (__all(v >= t)) break;
          __builtin_amdgcn_s_sleep(1);
        }
        __builtin_amdgcn_sched_barrier(0);
        asm volatile("" ::: "memory");
        const uint4* hp = (const uint4*)(h0 + ((size_t)(t - 1) * B_ + bb) * H_);
        uint4 tmp[4];
#pragma unroll
        for (int j = 0; j < 4; ++j) tmp[j] = hp[tid + j * 256];
#pragma unroll
        for (int j = 0; j < 4; ++j) {
          int ch = tid + j * 256;
          int b = ch >> 6, g = ch & 63;
          *(uint4*)&hbufA[g * 128 + ((b ^ (g & 15)) * 8)] = tmp[j];
        }
      }
      // ---- 4. x(t+1) -> other dbuf half ----
      if (hasx) {
        unsigned short* xd = bufB + ((t + 1) & 1) * 4096;
#pragma unroll
        for (int j = 0; j < 2; ++j) {
          int ch = tid + j * 256;
          int b = ch >> 5, g = ch & 31;
          *(uint4*)&xd[g * 128 + ((b ^ (g & 15)) * 8)] = xv[j];
        }
      }
      __syncthreads();
      // ---- 5. h-part MFMAs ----
      if (t > 0) {
#pragma unroll
        for (int kk = 0; kk < 16; kk += 2) {
          int g0 = kk * 4 + l4, g1 = (kk + 1) * 4 + l4;
          short8 a0 = *(const short8*)&hbufA[g0 * 128 + ((l15 ^ (g0 & 15)) * 8)];
          short8 a1 = *(const short8*)&hbufA[g1 * 128 + ((l15 ^ (g1 & 15)) * 8)];
          aE = __builtin_amdgcn_mfma_f32_16x16x32_bf16(a0, whh[kk], aE, 0, 0, 0);
          aO = __builtin_amdgcn_mfma_f32_16x16x32_bf16(a1, whh[kk + 1], aO, 0, 0, 0);
        }
      }
      f32x4 acc = aE + aO;
      // ---- 6. gate exchange ----
#pragma unroll
      for (int r = 0; r < 4; ++r) gbuf[(wv * 64 + lane) * 5 + r] = acc[r];
      __syncthreads();
      // ---- 7. cell update (1 cell/thread) ----
      {
        float g4[4];
#pragma unroll
        for (int s = 0; s < 4; ++s) g4[s] = gbuf[(s * 64 + lp) * 5 + ur] + b0s[s];
        float iv = sigmoidf_(g4[0]), fv = sigmoidf_(g4[1]);
        float gv = tanhf_(g4[2]), ov = sigmoidf_(g4[3]);
        cst = fv * cst + iv * gv;
        hstage[ubat * 20 + ucol] = f2bf(ov * tanhf_(cst));
      }
      __syncthreads();
      // ---- 8. publish ----
      if (tid < 64) {
        int bl = tid >> 2, q = tid & 3;
        unsigned long long v = *(const unsigned long long*)&hstage[bl * 20 + q * 4];
        cohstore_u64((unsigned long long*)(h0 + ((size_t)t * B_ + bb + bl) * H_ + colb) + q, v);
      }
      asm volatile("s_waitcnt vmcnt(0)" ::: "memory");
      __syncthreads();
      if (tid == 0) cohstore_i32(myflag, t + 1);
    }
  } else {
    // ================= LAYER 1 =================
    short8 wA[16], wB[16];
    {
      const float* wrA = wih1 + (size_t)(wv * H_ + colb + l15) * H_ + l4 * 8;
      const float* wrB = whh1 + (size_t)(wv * H_ + colb + l15) * H_ + l4 * 8;
#pragma unroll
      for (int kk = 0; kk < 16; ++kk) {
        float4 a0 = *(const float4*)(wrA + kk * 32);
        float4 a1 = *(const float4*)(wrA + kk * 32 + 4);
        unsigned short oa[8] = { f2bf(a0.x), f2bf(a0.y), f2bf(a0.z), f2bf(a0.w),
                                 f2bf(a1.x), f2bf(a1.y), f2bf(a1.z), f2bf(a1.w) };
        wA[kk] = *(const short8*)oa;
        float4 b0 = *(const float4*)(wrB + kk * 32);
        float4 b1 = *(const float4*)(wrB + kk * 32 + 4);
        unsigned short ob[8] = { f2bf(b0.x), f2bf(b0.y), f2bf(b0.z), f2bf(b0.w),
                                 f2bf(b1.x), f2bf(b1.y), f2bf(b1.z), f2bf(b1.w) };
        wB[kk] = *(const short8*)ob;
      }
    }
    float b1s[4];
#pragma unroll
    for (int s = 0; s < 4; ++s)
      b1s[s] = bih1[s * H_ + colb + ucol] + bhh1[s * H_ + colb + ucol];
    float cst = 0.f;

    for (int t = 0; t < T_; ++t) {
      // ---- wait h0(t) (cross-XCD), issue reg prefetch so it lands under B-phase ----
      for (;;) {
        int v = (lane < 32) ? cohload_i32(f_l0 + lane * 32) : 0x7fffffff;
        if (__all(v >= t + 1)) break;
        __builtin_amdgcn_s_sleep(1);
      }
      __builtin_amdgcn_sched_barrier(0);
      asm volatile("" ::: "memory");
      uint4 ha[4];
      {
        const uint4* hp = (const uint4*)(h0 + ((size_t)t * B_ + bb) * H_);
#pragma unroll
        for (int j = 0; j < 4; ++j) ha[j] = hp[tid + j * 256];
      }
      // ---- own-layer h1(t-1): wait (group-local), stage to LDS ----
      if (t > 0) {
        for (;;) {
          int v = (lane < 32) ? cohload_i32(f_own + lane * 32) : 0x7fffffff;
          if (__all(v >= t)) break;
          __builtin_amdgcn_s_sleep(1);
        }
        __builtin_amdgcn_sched_barrier(0);
        asm volatile("" ::: "memory");
        const uint4* hp = (const uint4*)(h1 + ((size_t)(t - 1) * B_ + bb) * H_);
        uint4 hbv[4];
#pragma unroll
        for (int j = 0; j < 4; ++j) hbv[j] = hp[tid + j * 256];
#pragma unroll
        for (int j = 0; j < 4; ++j) {
          int ch = tid + j * 256;
          int b = ch >> 6, g = ch & 63;
          *(uint4*)&bufB[g * 128 + ((b ^ (g & 15)) * 8)] = hbv[j];
        }
      }
      __syncthreads();
      // ---- B-phase MFMAs (h0 prefetch still in flight) ----
      f32x4 bE = {}, bO = {};
      if (t > 0) {
#pragma unroll
        for (int kk = 0; kk < 16; kk += 2) {
          int g0 = kk * 4 + l4, g1 = (kk + 1) * 4 + l4;
          short8 a0 = *(const short8*)&bufB[g0 * 128 + ((l15 ^ (g0 & 15)) * 8)];
          short8 a1 = *(const short8*)&bufB[g1 * 128 + ((l15 ^ (g1 & 15)) * 8)];
          bE = __builtin_amdgcn_mfma_f32_16x16x32_bf16(a0, wB[kk], bE, 0, 0, 0);
          bO = __builtin_amdgcn_mfma_f32_16x16x32_bf16(a1, wB[kk + 1], bO, 0, 0, 0);
        }
      }
      // ---- h0 regs -> LDS ----
#pragma unroll
      for (int j = 0; j < 4; ++j) {
        int ch = tid + j * 256;
        int b = ch >> 6, g = ch & 63;
        *(uint4*)&hbufA[g * 128 + ((b ^ (g & 15)) * 8)] = ha[j];
      }
      __syncthreads();
      // ---- A-phase MFMAs ----
      f32x4 aE = {}, aO = {};
#pragma unroll
      for (int kk = 0; kk < 16; kk += 2) {
        int g0 = kk * 4 + l4, g1 = (kk + 1) * 4 + l4;
        short8 a0 = *(const short8*)&hbufA[g0 * 128 + ((l15 ^ (g0 & 15)) * 8)];
        short8 a1 = *(const short8*)&hbufA[g1 * 128 + ((l15 ^ (g1 & 15)) * 8)];
        aE = __builtin_amdgcn_mfma_f32_16x16x32_bf16(a0, wA[kk], aE, 0, 0, 0);
        aO = __builtin_amdgcn_mfma_f32_16x16x32_bf16(a1, wA[kk + 1], aO, 0, 0, 0);
      }
      f32x4 acc = (aE + aO) + (bE + bO);
      // ---- exchange + update + publish ----
#pragma unroll
      for (int r = 0; r < 4; ++r) gbuf[(wv * 64 + lane) * 5 + r] = acc[r];
      __syncthreads();
      {
        float g4[4];
#pragma unroll
        for (int s = 0; s < 4; ++s) g4[s] = gbuf[(s * 64 + lp) * 5 + ur] + b1s[s];
        float iv = sigmoidf_(g4[0]), fv = sigmoidf_(g4[1]);
        float gv = tanhf_(g4[2]), ov = sigmoidf_(g4[3]);
        cst = fv * cst + iv * gv;
        hstage[ubat * 20 + ucol] = f2bf(ov * tanhf_(cst));
      }
      __syncthreads();
      if (tid < 64) {
        int bl = tid >> 2, q = tid & 3;
        unsigned long long v = *(const unsigned long long*)&hstage[bl * 20 + q * 4];
        cohstore_u64((unsigned long long*)(h1 + ((size_t)t * B_ + bb + bl) * H_ + colb) + q, v);
      }
      asm volatile("s_waitcnt vmcnt(0)" ::: "memory");
      __syncthreads();
      if (tid == 0) cohstore_i32(myflag, t + 1);
    }
  }
}

// ---------------- final FC + sigmoid ----------------
__global__ void k_fc(const unsigned short* __restrict__ h1, const float* __restrict__ w,
                     const float* __restrict__ bfc, float* __restrict__ out) {
  int b = threadIdx.x;
  if (b < B_) {
    const unsigned short* hb = h1 + ((size_t)(T_ - 1) * B_ + b) * H_;
    float s = 0.f;
    for (int j = 0; j < H_; ++j) s += bf2f(hb[j]) * w[j];
    out[b] = sigmoidf_(s + bfc[0]);
  }
}

extern "C" void kernel_launch(void* const* d_in, const int* in_sizes, int n_in,
                              void* d_out, int out_size, void* d_ws, size_t ws_size,
                              hipStream_t stream) {
  (void)in_sizes; (void)n_in; (void)out_size; (void)ws_size;
  const float* x    = (const float*)d_in[0];
  const float* wih0 = (const float*)d_in[1];
  const float* whh0 = (const float*)d_in[2];
  const float* bih0 = (const float*)d_in[3];
  const float* bhh0 = (const float*)d_in[4];
  const float* wih1 = (const float*)d_in[5];
  const float* whh1 = (const float*)d_in[6];
  const float* bih1 = (const float*)d_in[7];
  const float* bhh1 = (const float*)d_in[8];
  const float* wfc  = (const float*)d_in[9];
  const float* bfc  = (const float*)d_in[10];
  float* out = (float*)d_out;

  const size_t HB = (size_t)T_ * B_ * H_ * 2;   // 33.55MB per layer
  char* ws = (char*)d_ws;
  int* flg = (int*)ws;                          // 256 x 128B flag lines = 32KB
  unsigned short* h0 = (unsigned short*)(ws + 32768);
  unsigned short* h1 = (unsigned short*)(ws + 32768 + HB);
  unsigned short* xT = (unsigned short*)(ws + 32768 + 2 * HB);

  hipMemsetAsync(ws, 0, 32768, stream);   // flags must start at 0 each replay
  k_convert_x<<<2048, 256, 0, stream>>>(x, xT);
  k_lstm9<<<NWGF, 256, 0, stream>>>(xT, wih0, whh0, bih0, bhh0,
                                    wih1, whh1, bih1, bhh1, h0, h1, flg);
  k_fc<<<1, 64, 0, stream>>>(h1, wfc, bfc, out);
}

// Round 10
// 1726.417 us; speedup vs baseline: 5.2488x; 1.0669x over previous
//
#include <hip/hip_runtime.h>
#include <stdint.h>
#include <stddef.h>

#define B_ 64
#define T_ 512
#define DIN 256
#define H_ 512
#define NWGF 256     // 8 groups (layer x batch-quarter) x 32 col-group WGs

typedef __attribute__((ext_vector_type(8))) short short8;
typedef __attribute__((ext_vector_type(4))) float f32x4;

typedef const __attribute__((address_space(1))) unsigned int* gas_ptr;
typedef __attribute__((address_space(3))) unsigned int* las_ptr;

__device__ __forceinline__ unsigned short f2bf(float f) {
  union { float f; unsigned u; } v; v.f = f;
  return (unsigned short)((v.u + 0x7fffu + ((v.u >> 16) & 1u)) >> 16);
}
__device__ __forceinline__ float bf2f(unsigned short s) {
  union { unsigned u; float f; } v; v.u = ((unsigned)s) << 16; return v.f;
}
__device__ __forceinline__ float sigmoidf_(float x) { return 1.f / (1.f + __expf(-x)); }
__device__ __forceinline__ float tanhf_(float x) { return 1.f - 2.f / (__expf(2.f * x) + 1.f); }

// coherent (LLC, sc0|sc1) accesses for h stores + flags; no cache maintenance
__device__ __forceinline__ void cohstore_u32(unsigned* p, unsigned v) {
  __hip_atomic_store(p, v, __ATOMIC_RELAXED, __HIP_MEMORY_SCOPE_AGENT);
}
__device__ __forceinline__ int cohload_i32(const int* p) {
  return __hip_atomic_load(p, __ATOMIC_RELAXED, __HIP_MEMORY_SCOPE_AGENT);
}
__device__ __forceinline__ void cohstore_i32(int* p, int v) {
  __hip_atomic_store(p, v, __ATOMIC_RELAXED, __HIP_MEMORY_SCOPE_AGENT);
}

__device__ __forceinline__ void gload_lds16(const void* g, void* l) {
  __builtin_amdgcn_global_load_lds((gas_ptr)g, (las_ptr)l, 16, 0, 0);
}

// stage a 16x512 bf16 tile into LDS via global_load_lds: LDS dest is linear
// (wave-uniform base + lane*16 by HW); the SWIZZLE lives in the per-lane global
// source index (m173 pattern). Forward map: elem(b,g) = g*128 + ((b^(g&15))*8).
// Inverse for linear chunk u: g = u>>4, b = (u&15)^(g&15).
__device__ __forceinline__ void stage_tile_gl(const unsigned short* __restrict__ src,
                                              unsigned short* __restrict__ dst, int tid) {
#pragma unroll
  for (int j = 0; j < 4; ++j) {
    int u = tid + j * 256;
    int g = u >> 4, b = (u & 15) ^ (g & 15);
    gload_lds16(src + (size_t)b * H_ + g * 8,
                dst + (size_t)((tid & ~63) + j * 256) * 8);
  }
}

// ---------------- convert: x [B,T,DIN] f32 -> xT [T,B,DIN] bf16 ----------------
__global__ void k_convert_x(const float* __restrict__ x, unsigned short* __restrict__ xT) {
  const int nq = T_ * B_ * DIN / 4;
  for (int q = blockIdx.x * blockDim.x + threadIdx.x; q < nq; q += gridDim.x * blockDim.x) {
    int e = q * 4;
    int d = e % DIN;
    int row = e / DIN;            // t*B + b
    int b = row & (B_ - 1), t = row / B_;
    float4 v = *(const float4*)(x + ((size_t)b * T_ + t) * DIN + d);
    unsigned short o[4] = { f2bf(v.x), f2bf(v.y), f2bf(v.z), f2bf(v.w) };
    *(uint2*)(xT + (size_t)row * DIN + d) = *(const uint2*)o;
  }
}

// ---------------- fused 2-layer persistent LSTM (v10: shaved serial chain) ----------------
// Structure = v9 (8 XCD-local groups x 32 col-WGs, 1 WG/CU). Cuts vs v9:
// gload_lds staging (no VGPR roundtrip, linear LDS writes), no hstage (shfl-pack
// + direct u32 coherent stores from update), 3 barriers/tick, L1 combined poll,
// no-sleep polls.
__global__ __launch_bounds__(256, 1) void k_lstm10(
    const unsigned short* __restrict__ xT,   // [T,B,DIN] bf16
    const float* __restrict__ wih0, const float* __restrict__ whh0,
    const float* __restrict__ bih0, const float* __restrict__ bhh0,
    const float* __restrict__ wih1, const float* __restrict__ whh1,
    const float* __restrict__ bih1, const float* __restrict__ bhh1,
    unsigned short* __restrict__ h0, unsigned short* __restrict__ h1,  // [T,B,H]
    int* __restrict__ flg) {                 // 256 WGs x 128B flag lines
  __shared__ unsigned short hbufA[8192];   // 16KB h tile: elem g*128+((b^(g&15))*8)
  __shared__ unsigned short bufB[8192];    // 16KB: L0 = x dbuf [2][4096]; L1 = h1 tile
  __shared__ float gbuf[4 * 64 * 5];       // 5KB gate exchange (stride-5)
  const int bid = blockIdx.x;
  const int grp = bid & 7, cg = bid >> 3;
  const int layer = grp >> 2, bq = grp & 3;
  const int tid = threadIdx.x;
  const int lane = tid & 63, wv = tid >> 6;
  const int l15 = lane & 15, l4 = lane >> 4;
  const int colb = cg * 16, bb = bq * 16;
  const int ucol = tid & 15, ubat = tid >> 4;            // update cell (row=ubat,col=ucol)
  const int lp = (ubat >> 2) * 16 + ucol, ur = ubat & 3; // gbuf source for that cell
  int* myflag = flg + (grp * 32 + cg) * 32;
  const int* f_own = flg + (grp * 32) * 32;              // own group's flag block
  const int* f_l0  = flg + (bq * 32) * 32;               // layer-0 group (for L1)

  if (layer == 0) {
    // ================= LAYER 0 (x-fused) =================
    short8 wih[8], whh[16];
    {
      const float* wr = wih0 + (size_t)(wv * H_ + colb + l15) * DIN + l4 * 8;
#pragma unroll
      for (int kk = 0; kk < 8; ++kk) {
        float4 v0 = *(const float4*)(wr + kk * 32);
        float4 v1 = *(const float4*)(wr + kk * 32 + 4);
        unsigned short o[8] = { f2bf(v0.x), f2bf(v0.y), f2bf(v0.z), f2bf(v0.w),
                                f2bf(v1.x), f2bf(v1.y), f2bf(v1.z), f2bf(v1.w) };
        wih[kk] = *(const short8*)o;
      }
      const float* wr2 = whh0 + (size_t)(wv * H_ + colb + l15) * H_ + l4 * 8;
#pragma unroll
      for (int kk = 0; kk < 16; ++kk) {
        float4 v0 = *(const float4*)(wr2 + kk * 32);
        float4 v1 = *(const float4*)(wr2 + kk * 32 + 4);
        unsigned short o[8] = { f2bf(v0.x), f2bf(v0.y), f2bf(v0.z), f2bf(v0.w),
                                f2bf(v1.x), f2bf(v1.y), f2bf(v1.z), f2bf(v1.w) };
        whh[kk] = *(const short8*)o;
      }
    }
    float b0s[4];
#pragma unroll
    for (int s = 0; s < 4; ++s)
      b0s[s] = bih0[s * H_ + colb + ucol] + bhh0[s * H_ + colb + ucol];
    float cst = 0.f;

    // prologue: stage x(0) into dbuf half 0 (16 rows x 32 granules)
#pragma unroll
    for (int j = 0; j < 2; ++j) {
      int ch = tid + j * 256;
      int b = ch >> 5, g = ch & 31;
      uint4 v = *(const uint4*)(xT + (size_t)(bb + b) * DIN + g * 8);
      *(uint4*)&bufB[g * 128 + ((b ^ (g & 15)) * 8)] = v;
    }
    __syncthreads();

    for (int t = 0; t < T_; ++t) {
      // ---- 1. x-part MFMAs ----
      f32x4 aE = {}, aO = {};
      {
        const unsigned short* xb = bufB + (t & 1) * 4096;
#pragma unroll
        for (int kk = 0; kk < 8; kk += 2) {
          int g0 = kk * 4 + l4, g1 = (kk + 1) * 4 + l4;
          short8 a0 = *(const short8*)&xb[g0 * 128 + ((l15 ^ (g0 & 15)) * 8)];
          short8 a1 = *(const short8*)&xb[g1 * 128 + ((l15 ^ (g1 & 15)) * 8)];
          aE = __builtin_amdgcn_mfma_f32_16x16x32_bf16(a0, wih[kk], aE, 0, 0, 0);
          aO = __builtin_amdgcn_mfma_f32_16x16x32_bf16(a1, wih[kk + 1], aO, 0, 0, 0);
        }
      }
      // ---- 2. reg-prefetch x(t+1) ----
      uint4 xv[2];
      const bool hasx = (t + 1 < T_);
      if (hasx) {
        const unsigned short* xs = xT + (size_t)(t + 1) * (B_ * DIN);
#pragma unroll
        for (int j = 0; j < 2; ++j) {
          int ch = tid + j * 256;
          xv[j] = *(const uint4*)(xs + (size_t)(bb + (ch >> 5)) * DIN + (ch & 31) * 8);
        }
      }
      // ---- 3. wait h0(t-1) flags, stage via global_load_lds ----
      if (t > 0) {
        for (;;) {
          int v = (lane < 32) ? cohload_i32(f_own + lane * 32) : 0x7fffffff;
          if (__all(v >= t)) break;
        }
        __builtin_amdgcn_sched_barrier(0);
        asm volatile("" ::: "memory");
        stage_tile_gl(h0 + ((size_t)(t - 1) * B_ + bb) * H_, hbufA, tid);
      }
      // ---- 4. x(t+1) -> other dbuf half ----
      if (hasx) {
        unsigned short* xd = bufB + ((t + 1) & 1) * 4096;
#pragma unroll
        for (int j = 0; j < 2; ++j) {
          int ch = tid + j * 256;
          int b = ch >> 5, g = ch & 31;
          *(uint4*)&xd[g * 128 + ((b ^ (g & 15)) * 8)] = xv[j];
        }
      }
      __syncthreads();   // barrier 1: drains gload_lds (vmcnt) + x ds_writes
      // ---- 5. h-part MFMAs ----
      if (t > 0) {
#pragma unroll
        for (int kk = 0; kk < 16; kk += 2) {
          int g0 = kk * 4 + l4, g1 = (kk + 1) * 4 + l4;
          short8 a0 = *(const short8*)&hbufA[g0 * 128 + ((l15 ^ (g0 & 15)) * 8)];
          short8 a1 = *(const short8*)&hbufA[g1 * 128 + ((l15 ^ (g1 & 15)) * 8)];
          aE = __builtin_amdgcn_mfma_f32_16x16x32_bf16(a0, whh[kk], aE, 0, 0, 0);
          aO = __builtin_amdgcn_mfma_f32_16x16x32_bf16(a1, whh[kk + 1], aO, 0, 0, 0);
        }
      }
      f32x4 acc = aE + aO;
      // ---- 6. gate exchange ----
#pragma unroll
      for (int r = 0; r < 4; ++r) gbuf[(wv * 64 + lane) * 5 + r] = acc[r];
      __syncthreads();   // barrier 2
      // ---- 7. cell update -> shfl-pack -> direct u32 coherent store ----
      {
        float g4[4];
#pragma unroll
        for (int s = 0; s < 4; ++s) g4[s] = gbuf[(s * 64 + lp) * 5 + ur] + b0s[s];
        float iv = sigmoidf_(g4[0]), fv = sigmoidf_(g4[1]);
        float gv = tanhf_(g4[2]), ov = sigmoidf_(g4[3]);
        cst = fv * cst + iv * gv;
        unsigned short hv = f2bf(ov * tanhf_(cst));
        unsigned pv = (unsigned)hv | (((unsigned)__shfl_xor((int)hv, 1, 64)) << 16);
        if (!(lane & 1))
          cohstore_u32((unsigned*)(h0 + ((size_t)t * B_ + bb + ubat) * H_ + colb + ucol), pv);
      }
      asm volatile("s_waitcnt vmcnt(0)" ::: "memory");
      __syncthreads();   // barrier 3: all threads' stores drained
      if (tid == 0) cohstore_i32(myflag, t + 1);
    }
  } else {
    // ================= LAYER 1 =================
    short8 wA[16], wB[16];
    {
      const float* wrA = wih1 + (size_t)(wv * H_ + colb + l15) * H_ + l4 * 8;
      const float* wrB = whh1 + (size_t)(wv * H_ + colb + l15) * H_ + l4 * 8;
#pragma unroll
      for (int kk = 0; kk < 16; ++kk) {
        float4 a0 = *(const float4*)(wrA + kk * 32);
        float4 a1 = *(const float4*)(wrA + kk * 32 + 4);
        unsigned short oa[8] = { f2bf(a0.x), f2bf(a0.y), f2bf(a0.z), f2bf(a0.w),
                                 f2bf(a1.x), f2bf(a1.y), f2bf(a1.z), f2bf(a1.w) };
        wA[kk] = *(const short8*)oa;
        float4 b0 = *(const float4*)(wrB + kk * 32);
        float4 b1 = *(const float4*)(wrB + kk * 32 + 4);
        unsigned short ob[8] = { f2bf(b0.x), f2bf(b0.y), f2bf(b0.z), f2bf(b0.w),
                                 f2bf(b1.x), f2bf(b1.y), f2bf(b1.z), f2bf(b1.w) };
        wB[kk] = *(const short8*)ob;
      }
    }
    float b1s[4];
#pragma unroll
    for (int s = 0; s < 4; ++s)
      b1s[s] = bih1[s * H_ + colb + ucol] + bhh1[s * H_ + colb + ucol];
    float cst = 0.f;

    for (int t = 0; t < T_; ++t) {
      // ---- combined poll: lanes 0..31 watch f_l0 >= t+1, lanes 32..63 watch f_own >= t ----
      {
        const int* fp = (lane < 32) ? (f_l0 + lane * 32) : (f_own + (lane - 32) * 32);
        const int need = (lane < 32) ? (t + 1) : t;
        for (;;) {
          int v = cohload_i32(fp);
          if (__all(v >= need)) break;
        }
      }
      __builtin_amdgcn_sched_barrier(0);
      asm volatile("" ::: "memory");
      // ---- stage h0(t) and h1(t-1) concurrently via global_load_lds ----
      stage_tile_gl(h0 + ((size_t)t * B_ + bb) * H_, hbufA, tid);
      if (t > 0)
        stage_tile_gl(h1 + ((size_t)(t - 1) * B_ + bb) * H_, bufB, tid);
      __syncthreads();   // barrier 1: vmcnt drained
      // ---- all MFMAs (A: h0 @ Wih1, B: h1 @ Whh1), 4 independent chains ----
      f32x4 aE = {}, aO = {}, bE = {}, bO = {};
      if (t > 0) {
#pragma unroll
        for (int kk = 0; kk < 16; kk += 2) {
          int g0 = kk * 4 + l4, g1 = (kk + 1) * 4 + l4;
          int e0 = g0 * 128 + ((l15 ^ (g0 & 15)) * 8);
          int e1 = g1 * 128 + ((l15 ^ (g1 & 15)) * 8);
          aE = __builtin_amdgcn_mfma_f32_16x16x32_bf16(*(const short8*)&hbufA[e0], wA[kk], aE, 0, 0, 0);
          aO = __builtin_amdgcn_mfma_f32_16x16x32_bf16(*(const short8*)&hbufA[e1], wA[kk + 1], aO, 0, 0, 0);
          bE = __builtin_amdgcn_mfma_f32_16x16x32_bf16(*(const short8*)&bufB[e0], wB[kk], bE, 0, 0, 0);
          bO = __builtin_amdgcn_mfma_f32_16x16x32_bf16(*(const short8*)&bufB[e1], wB[kk + 1], bO, 0, 0, 0);
        }
      } else {
#pragma unroll
        for (int kk = 0; kk < 16; kk += 2) {
          int g0 = kk * 4 + l4, g1 = (kk + 1) * 4 + l4;
          int e0 = g0 * 128 + ((l15 ^ (g0 & 15)) * 8);
          int e1 = g1 * 128 + ((l15 ^ (g1 & 15)) * 8);
          aE = __builtin_amdgcn_mfma_f32_16x16x32_bf16(*(const short8*)&hbufA[e0], wA[kk], aE, 0, 0, 0);
          aO = __builtin_amdgcn_mfma_f32_16x16x32_bf16(*(const short8*)&hbufA[e1], wA[kk + 1], aO, 0, 0, 0);
        }
      }
      f32x4 acc = (aE + aO) + (bE + bO);
      // ---- exchange + update + pack-store + publish ----
#pragma unroll
      for (int r = 0; r < 4; ++r) gbuf[(wv * 64 + lane) * 5 + r] = acc[r];
      __syncthreads();   // barrier 2
      {
        float g4[4];
#pragma unroll
        for (int s = 0; s < 4; ++s) g4[s] = gbuf[(s * 64 + lp) * 5 + ur] + b1s[s];
        float iv = sigmoidf_(g4[0]), fv = sigmoidf_(g4[1]);
        float gv = tanhf_(g4[2]), ov = sigmoidf_(g4[3]);
        cst = fv * cst + iv * gv;
        unsigned short hv = f2bf(ov * tanhf_(cst));
        unsigned pv = (unsigned)hv | (((unsigned)__shfl_xor((int)hv, 1, 64)) << 16);
        if (!(lane & 1))
          cohstore_u32((unsigned*)(h1 + ((size_t)t * B_ + bb + ubat) * H_ + colb + ucol), pv);
      }
      asm volatile("s_waitcnt vmcnt(0)" ::: "memory");
      __syncthreads();   // barrier 3
      if (tid == 0) cohstore_i32(myflag, t + 1);
    }
  }
}

// ---------------- final FC + sigmoid ----------------
__global__ void k_fc(const unsigned short* __restrict__ h1, const float* __restrict__ w,
                     const float* __restrict__ bfc, float* __restrict__ out) {
  int b = threadIdx.x;
  if (b < B_) {
    const unsigned short* hb = h1 + ((size_t)(T_ - 1) * B_ + b) * H_;
    float s = 0.f;
    for (int j = 0; j < H_; ++j) s += bf2f(hb[j]) * w[j];
    out[b] = sigmoidf_(s + bfc[0]);
  }
}

extern "C" void kernel_launch(void* const* d_in, const int* in_sizes, int n_in,
                              void* d_out, int out_size, void* d_ws, size_t ws_size,
                              hipStream_t stream) {
  (void)in_sizes; (void)n_in; (void)out_size; (void)ws_size;
  const float* x    = (const float*)d_in[0];
  const float* wih0 = (const float*)d_in[1];
  const float* whh0 = (const float*)d_in[2];
  const float* bih0 = (const float*)d_in[3];
  const float* bhh0 = (const float*)d_in[4];
  const float* wih1 = (const float*)d_in[5];
  const float* whh1 = (const float*)d_in[6];
  const float* bih1 = (const float*)d_in[7];
  const float* bhh1 = (const float*)d_in[8];
  const float* wfc  = (const float*)d_in[9];
  const float* bfc  = (const float*)d_in[10];
  float* out = (float*)d_out;

  const size_t HB = (size_t)T_ * B_ * H_ * 2;   // 33.55MB per layer
  char* ws = (char*)d_ws;
  int* flg = (int*)ws;                          // 256 x 128B flag lines = 32KB
  unsigned short* h0 = (unsigned short*)(ws + 32768);
  unsigned short* h1 = (unsigned short*)(ws + 32768 + HB);
  unsigned short* xT = (unsigned short*)(ws + 32768 + 2 * HB);

  hipMemsetAsync(ws, 0, 32768, stream);   // flags must start at 0 each replay
  k_convert_x<<<2048, 256, 0, stream>>>(x, xT);
  k_lstm10<<<NWGF, 256, 0, stream>>>(xT, wih0, whh0, bih0, bhh0,
                                     wih1, whh1, bih1, bhh1, h0, h1, flg);
  k_fc<<<1, 64, 0, stream>>>(h1, wfc, bfc, out);
}